// Round 8
// baseline (774.725 us; speedup 1.0000x reference)
//
#include <hip/hip_runtime.h>

typedef unsigned short u16;
typedef unsigned int u32;

#define BB 64
#define FF 4096
#define DD 192
#define HH 768

typedef __attribute__((ext_vector_type(8))) __bf16 bf16x8;
typedef __attribute__((ext_vector_type(4))) float f32x4;

__device__ __forceinline__ float bf2f(u32 u) {
  union { u32 i; float f; } x; x.i = u << 16; return x.f;
}
__device__ __forceinline__ u16 f2bf(float f) {
  __bf16 h = (__bf16)f;
  return __builtin_bit_cast(u16, h);
}
__device__ __forceinline__ u32 pk2bf(float a, float b) {
  return (u32)f2bf(a) | ((u32)f2bf(b) << 16);
}
__device__ __forceinline__ float sigm(float x) { return 1.f / (1.f + __expf(-x)); }

// ---------------------------------------------------------------------------
// Prep: Wvm[e][d] = g[e]*Wv[e][d] (f32), s0v[d] = b@Wv, s0k[d] = b@Wk.
// ---------------------------------------------------------------------------
__global__ void prep_vw(const float* __restrict__ Wk, const float* __restrict__ Wv,
                        const float* __restrict__ g, const float* __restrict__ bb,
                        float* __restrict__ Wvm, float* __restrict__ s0v,
                        float* __restrict__ s0k) {
  int d = threadIdx.x;  // 0..191
  float av = 0.f, ak = 0.f;
  for (int e = 0; e < DD; ++e) {
    float wv = Wv[e * DD + d];
    Wvm[e * DD + d] = g[e] * wv;
    av += bb[e] * wv;
    ak += bb[e] * Wk[e * DD + d];
  }
  s0v[d] = av; s0k[d] = ak;
}

// Pack GRU/MLP weights to bf16 e-pairs: dst[((g*E2+e/2)*N + n)*2 + (e&1)].
__global__ void prep_packw(const float* __restrict__ Wih, const float* __restrict__ Whh,
                           const float* __restrict__ W1, const float* __restrict__ W2,
                           u16* __restrict__ pWih, u16* __restrict__ pWhh,
                           u16* __restrict__ pW1, u16* __restrict__ pW2) {
  int which = blockIdx.y;
  int total, N, E;
  const float* src; u16* dst; int srcEmajor;
  if (which < 2) { total = 3 * 576 * 192; N = 576; E = 192; srcEmajor = 0;
                   src = which ? Whh : Wih; dst = which ? pWhh : pWih; }
  else if (which == 2) { total = 3 * 192 * 768; N = 768; E = 192; srcEmajor = 1;
                         src = W1; dst = pW1; }
  else { total = 3 * 768 * 192; N = 192; E = 768; srcEmajor = 1; src = W2; dst = pW2; }
  for (int idx = blockIdx.x * 256 + threadIdx.x; idx < total; idx += gridDim.x * 256) {
    int g = idx / (N * E), rem = idx % (N * E);
    int n, e;
    if (srcEmajor) { e = rem / N; n = rem % N; }    // src[g][e][n]
    else { n = rem / E; e = rem % E; }              // src[g][n][e]
    dst[((g * (E / 2) + (e >> 1)) * N + n) * 2 + (e & 1)] = f2bf(src[idx]);
  }
}

// ---------------------------------------------------------------------------
// Fused fconv + iteration-1 attention:
// per 64-token block: stage f (f32->bf16, stats, fb write, swizzled LDS tile),
// gather PV B-granules into regs (also written to fd for iters 2,3),
// QK from LDS (A=p), softmax (no bias at it0), PV from regs, atomics.
// ---------------------------------------------------------------------------
__global__ __launch_bounds__(256) void fconv_attn1(
    const float* __restrict__ feat, u16* __restrict__ fb, u16* __restrict__ fd,
    float2* __restrict__ stats, const u16* __restrict__ pbuf,
    const float* __restrict__ pab, float* __restrict__ U,
    float* __restrict__ scal_cur) {
  __shared__ __align__(16) u16 flds[64 * 192];    // 24.6 KB swizzled token-major
  __shared__ __align__(16) u16 plds[16 * 192];    // 6.1 KB
  __shared__ __align__(16) u16 attn_lds[16 * 64]; // 2 KB swizzled [slot][token]
  __shared__ float stat_l[64 * 2];
  int tid = threadIdx.x;
  int blk = blockIdx.x;
  int b = blk >> 6;
  int w = tid >> 6, lane = tid & 63;
  int l15 = lane & 15, l4 = lane >> 4;
  // ---- stage p (swizzled) + zero attn rows 8..15 ----
  #pragma unroll
  for (int i = 0; i < 2; ++i) {
    int g = tid + i * 256;
    if (g < 384) {
      int s = g / 24, u = g % 24;
      uint4 v = *(const uint4*)(pbuf + ((b * 16 + s) * DD + u * 8));
      *(uint4*)((char*)plds + s * 384 + ((u ^ (s & 7)) << 4)) = v;
    }
  }
  if (tid < 64) *(uint4*)((char*)attn_lds + 1024 + tid * 16) = (uint4){0, 0, 0, 0};
  // ---- stage f: thread (r = token, p = 48-dim slice) ----
  {
    int r = tid >> 2, p = tid & 3;
    long t = (long)blk * 64 + r;
    const float4* src = (const float4*)(feat + t * DD) + p * 12;
    float s = 0.f, s2 = 0.f;
    long Tg = t >> 4; int tau = (int)(t & 15);
    #pragma unroll
    for (int i = 0; i < 6; ++i) {
      float4 a = src[i * 2], c = src[i * 2 + 1];
      s += a.x + a.y + a.z + a.w + c.x + c.y + c.z + c.w;
      s2 += a.x * a.x + a.y * a.y + a.z * a.z + a.w * a.w +
            c.x * c.x + c.y * c.y + c.z * c.z + c.w * c.w;
      uint4 v;
      v.x = pk2bf(a.x, a.y); v.y = pk2bf(a.z, a.w);
      v.z = pk2bf(c.x, c.y); v.w = pk2bf(c.z, c.w);
      int u = p * 6 + i;
      *(uint4*)(fb + ((Tg * 24 + u) * 16 + tau) * 8) = v;
      *(uint4*)((char*)flds + r * 384 + ((u ^ (r & 7)) << 4)) = v;
    }
    s += __shfl_xor(s, 1); s2 += __shfl_xor(s2, 1);
    s += __shfl_xor(s, 2); s2 += __shfl_xor(s2, 2);
    if (p == 0) {
      float mu = s * (1.f / 192.f);
      float rstd = rsqrtf(s2 * (1.f / 192.f) - mu * mu + 1e-5f);
      stats[t] = make_float2(rstd, mu);
      stat_l[r * 2] = rstd; stat_l[r * 2 + 1] = mu;
    }
  }
  __syncthreads();
  // ---- gather PV granules to regs + write fd ----
  uint4 gran[6];
  #pragma unroll
  for (int i = 0; i < 6; ++i) {
    int pair = w * 6 + i;
    int nt = pair >> 1, ks = pair & 1;
    int d = nt * 16 + l15;
    u16 h[8];
    #pragma unroll
    for (int j = 0; j < 8; ++j) {
      int tok = ks * 32 + l4 * 8 + j;
      h[j] = *(const u16*)((char*)flds + tok * 384 +
                           (((d >> 3) ^ (tok & 7)) << 4) + (d & 7) * 2);
    }
    uint4 v;
    v.x = (u32)h[0] | ((u32)h[1] << 16);
    v.y = (u32)h[2] | ((u32)h[3] << 16);
    v.z = (u32)h[4] | ((u32)h[5] << 16);
    v.w = (u32)h[6] | ((u32)h[7] << 16);
    gran[i] = v;
    int g32 = (blk & 63) * 2 + ks;
    *(uint4*)(fd + ((((long)b * 128 + g32) * 12 + nt) * 64 + l4 * 16 + l15) * 8) = v;
  }
  // ---- QK for tile w (tokens w*16..+15), no spatial bias at it=0 ----
  bf16x8 qfr[6];
  #pragma unroll
  for (int kk = 0; kk < 6; ++kk) {
    int u = kk * 4 + l4;
    qfr[kk] = *(bf16x8*)((char*)plds + l15 * 384 + ((u ^ (l15 & 7)) << 4));
  }
  float av[4], bv[4];
  #pragma unroll
  for (int j = 0; j < 4; ++j) {
    int s = l4 * 4 + j;
    av[j] = (s < 8) ? pab[(b * 8 + s) * 2] : 0.f;
    bv[j] = (s < 8) ? pab[(b * 8 + s) * 2 + 1] : 0.f;
  }
  {
    int tl = w * 16 + l15;               // block-local token
    f32x4 acc = (f32x4){0.f, 0.f, 0.f, 0.f};
    #pragma unroll
    for (int kk = 0; kk < 6; ++kk) {
      int u = kk * 4 + l4;
      bf16x8 bfr = *(bf16x8*)((char*)flds + tl * 384 + ((u ^ (tl & 7)) << 4));
      acc = __builtin_amdgcn_mfma_f32_16x16x32_bf16(qfr[kk], bfr, acc, 0, 0, 0);
    }
    float rstd = stat_l[tl * 2], muv = stat_l[tl * 2 + 1];
    int t = (blk & 63) * 64 + tl;        // batch-local token
    float x = -1.f + (float)(t & 63) * (2.f / 63.f);
    float y = -1.f + (float)(t >> 6) * (2.f / 63.f);
    float d4[4];
    #pragma unroll
    for (int j = 0; j < 4; ++j)
      d4[j] = rstd * acc[j] - rstd * muv * av[j] + bv[j];
    float o4[4];
    #pragma unroll
    for (int j = 0; j < 4; ++j) o4[j] = __shfl_xor(d4[j], 16);
    float mx = fmaxf(fmaxf(fmaxf(d4[0], d4[1]), fmaxf(d4[2], d4[3])),
                     fmaxf(fmaxf(o4[0], o4[1]), fmaxf(o4[2], o4[3])));
    float e4[4];
    float sum = 0.f;
    #pragma unroll
    for (int j = 0; j < 4; ++j) { e4[j] = __expf(d4[j] - mx); sum += e4[j]; }
    #pragma unroll
    for (int j = 0; j < 4; ++j) sum += __expf(o4[j] - mx);
    float inv = 1.f / sum;
    float pa[4], px[4], py[4], pg[4];
    #pragma unroll
    for (int j = 0; j < 4; ++j) { pa[j] = 0.f; px[j] = 0.f; py[j] = 0.f; pg[j] = 0.f; }
    if (l4 < 2) {
      #pragma unroll
      for (int j = 0; j < 4; ++j) {
        float a = e4[j] * inv;
        u16 wr = f2bf(a * rstd);
        int s = l4 * 4 + j;
        *(u16*)((char*)attn_lds + ((s * 128 + tl * 2) ^ ((s & 7) << 4))) = wr;
        pa[j] = a; px[j] = a * x; py[j] = a * y;
        pg[j] = bf2f(wr) * muv;
      }
    }
    #pragma unroll
    for (int m = 1; m < 16; m <<= 1) {
      #pragma unroll
      for (int j = 0; j < 4; ++j) {
        pa[j] += __shfl_xor(pa[j], m);
        px[j] += __shfl_xor(px[j], m);
        py[j] += __shfl_xor(py[j], m);
        pg[j] += __shfl_xor(pg[j], m);
      }
    }
    if (l15 == 0 && l4 < 2) {
      #pragma unroll
      for (int j = 0; j < 4; ++j) {
        int s = l4 * 4 + j;
        atomicAdd(&scal_cur[(b * 8 + s) * 4], pa[j]);
        atomicAdd(&scal_cur[(b * 8 + s) * 4 + 1], px[j]);
        atomicAdd(&scal_cur[(b * 8 + s) * 4 + 2], py[j]);
        atomicAdd(&scal_cur[(b * 8 + s) * 4 + 3], pg[j]);
      }
    }
  }
  __syncthreads();
  // ---- PV from register granules: acc over both K-steps per dim-tile ----
  f32x4 pacc[3];
  #pragma unroll
  for (int ni = 0; ni < 3; ++ni) pacc[ni] = (f32x4){0.f, 0.f, 0.f, 0.f};
  #pragma unroll
  for (int i = 0; i < 6; ++i) {
    int ks = (w * 6 + i) & 1;
    int tl0 = ks * 32 + l4 * 8;
    bf16x8 afr = *(bf16x8*)((char*)attn_lds + ((l15 * 128 + tl0 * 2) ^ ((l15 & 7) << 4)));
    pacc[i >> 1] = __builtin_amdgcn_mfma_f32_16x16x32_bf16(
        afr, __builtin_bit_cast(bf16x8, gran[i]), pacc[i >> 1], 0, 0, 0);
  }
  if (l4 < 2) {
    #pragma unroll
    for (int ni = 0; ni < 3; ++ni) {
      int nt = w * 3 + ni;
      #pragma unroll
      for (int j = 0; j < 4; ++j) {
        int s = l4 * 4 + j;
        atomicAdd(&U[((long)b * 8 + s) * DD + nt * 16 + l15], pacc[ni][j]);
      }
    }
  }
}

// ---------------------------------------------------------------------------
// q projection + p = g ⊙ (Wk @ q), alpha = sum(bf16(p)), beta = s0k·q.
// One wave per (b,slot).  Also zeroes U/scal_cur and pbuf rows 8..15.
// ---------------------------------------------------------------------------
__global__ __launch_bounds__(64) void qproj_kernel(
    const float* __restrict__ slots, const float* __restrict__ Wq,
    const float* __restrict__ lsg, const float* __restrict__ lsb,
    const float* __restrict__ Wk, const float* __restrict__ lfg,
    const float* __restrict__ s0k,
    u16* __restrict__ pbuf, float* __restrict__ pab,
    float* __restrict__ U, float* __restrict__ scal_cur) {
  __shared__ float ln[192];
  int bk = blockIdx.x;
  int b = bk >> 3, sl = bk & 7;
  int lane = threadIdx.x;
  {
    int gtid = bk * 64 + lane;
    float4 z = {0.f, 0.f, 0.f, 0.f};
    if (gtid < 24576) ((float4*)U)[gtid] = z;
    else if (gtid < 24576 + 512) ((float4*)scal_cur)[gtid - 24576] = z;
  }
  const float* x = slots + bk * DD;
  float v0 = x[lane], v1 = x[lane + 64], v2 = x[lane + 128];
  float s = v0 + v1 + v2, s2 = v0 * v0 + v1 * v1 + v2 * v2;
  #pragma unroll
  for (int m = 1; m < 64; m <<= 1) { s += __shfl_xor(s, m); s2 += __shfl_xor(s2, m); }
  float mu = s * (1.f / 192.f);
  float rstd = rsqrtf(s2 * (1.f / 192.f) - mu * mu + 1e-5f);
  ln[lane]       = (v0 - mu) * rstd * lsg[lane]       + lsb[lane];
  ln[lane + 64]  = (v1 - mu) * rstd * lsg[lane + 64]  + lsb[lane + 64];
  ln[lane + 128] = (v2 - mu) * rstd * lsg[lane + 128] + lsb[lane + 128];
  __syncthreads();
  float a0 = 0.f, a1 = 0.f, a2 = 0.f;
  for (int e = 0; e < DD; ++e) {
    float le = ln[e];
    a0 += le * Wq[e * DD + lane];
    a1 += le * Wq[e * DD + lane + 64];
    a2 += le * Wq[e * DD + lane + 128];
  }
  __syncthreads();
  const float scale = 0.07216878364870323f;  // 192^-0.5
  ln[lane] = a0 * scale; ln[lane + 64] = a1 * scale; ln[lane + 128] = a2 * scale;
  __syncthreads();
  float al = 0.f, be = 0.f;
  u16 pb[3];
  #pragma unroll
  for (int k3 = 0; k3 < 3; ++k3) {
    int d = lane + k3 * 64;
    const float* wr = Wk + (size_t)d * DD;
    float pd = 0.f;
    for (int e = 0; e < DD; ++e) pd += wr[e] * ln[e];
    pd *= lfg[d];
    u16 h = f2bf(pd);
    pb[k3] = h;
    al += bf2f(h);
    be += s0k[d] * ln[d];
  }
  #pragma unroll
  for (int m = 1; m < 64; m <<= 1) { al += __shfl_xor(al, m); be += __shfl_xor(be, m); }
  #pragma unroll
  for (int k3 = 0; k3 < 3; ++k3)
    pbuf[(b * 16 + sl) * DD + lane + k3 * 64] = pb[k3];
  if (lane < 24) *(uint4*)(pbuf + (b * 16 + 8 + sl) * DD + lane * 8) = (uint4){0, 0, 0, 0};
  if (lane == 0) { pab[bk * 2] = al; pab[bk * 2 + 1] = be; }
}

// ---------------------------------------------------------------------------
// Fused attention + update on raw features (iterations 2,3 — with bias).
// grid (B, 16): 256 tokens per block.
// ---------------------------------------------------------------------------
__global__ __launch_bounds__(256) void attnpv_kernel(
    const u16* __restrict__ fb, const u16* __restrict__ fd,
    const u16* __restrict__ pbuf, const float* __restrict__ pab,
    const float2* __restrict__ stats,
    const float* __restrict__ scal_prev,
    float* __restrict__ U, float* __restrict__ scal_cur) {
  __shared__ __align__(16) u16 plds[16 * 192];
  __shared__ __align__(16) u16 attn_lds[16 * 256];   // [slot][token], XOR-swizzled
  int b = blockIdx.x;
  int chunk = blockIdx.y * 256;
  int tid = threadIdx.x;
  #pragma unroll
  for (int i = 0; i < 2; ++i) {
    int g = tid + i * 256;
    if (g < 384) {
      int s = g / 24, u = g % 24;
      uint4 v = *(const uint4*)(pbuf + ((b * 16 + s) * DD + u * 8));
      *(uint4*)((char*)plds + s * 384 + ((u ^ (s & 7)) << 4)) = v;
    }
  }
  *(uint4*)((char*)attn_lds + 4096 + tid * 16) = (uint4){0, 0, 0, 0};
  __syncthreads();
  int w = tid >> 6, lane = tid & 63;
  int l15 = lane & 15, l4 = lane >> 4;
  bf16x8 qfr[6];
  #pragma unroll
  for (int kk = 0; kk < 6; ++kk) {
    int u = kk * 4 + l4;
    qfr[kk] = *(bf16x8*)((char*)plds + l15 * 384 + ((u ^ (l15 & 7)) << 4));
  }
  float ax[4], ay[4], c0[4], av[4], bv[4];
  #pragma unroll
  for (int j = 0; j < 4; ++j) {
    int s = l4 * 4 + j;
    if (s < 8) {
      av[j] = pab[(b * 8 + s) * 2];
      bv[j] = pab[(b * 8 + s) * 2 + 1];
      float inv = 1.f / (scal_prev[(b * 8 + s) * 4] + 1e-8f);
      float cx = scal_prev[(b * 8 + s) * 4 + 1] * inv;
      float cy = scal_prev[(b * 8 + s) * 4 + 2] * inv;
      ax[j] = 16.f * cx; ay[j] = 16.f * cy; c0[j] = -8.f * (cx * cx + cy * cy);
    } else { av[j] = 0.f; bv[j] = 0.f; ax[j] = 0.f; ay[j] = 0.f; c0[j] = 0.f; }
  }
  float pa[4], px[4], py[4], pg[4];
  #pragma unroll
  for (int j = 0; j < 4; ++j) { pa[j] = 0.f; px[j] = 0.f; py[j] = 0.f; pg[j] = 0.f; }
  for (int tile = w; tile < 16; tile += 4) {
    int t0 = chunk + tile * 16;
    long Tg = (long)b * 256 + (t0 >> 4);
    const u16* kp = fb + (Tg * 24 + l4) * 128 + l15 * 8;
    f32x4 acc = (f32x4){0.f, 0.f, 0.f, 0.f};
    #pragma unroll
    for (int kk = 0; kk < 6; ++kk) {
      bf16x8 bfr = *(const bf16x8*)(kp + kk * 512);
      acc = __builtin_amdgcn_mfma_f32_16x16x32_bf16(qfr[kk], bfr, acc, 0, 0, 0);
    }
    int t = t0 + l15;
    float2 st = stats[((long)b << 12) + t];
    float rstd = st.x, muv = st.y;
    float x = -1.f + (float)(t & 63) * (2.f / 63.f);
    float y = -1.f + (float)(t >> 6) * (2.f / 63.f);
    float m8r2 = -8.f * (x * x + y * y);
    float d4[4];
    #pragma unroll
    for (int j = 0; j < 4; ++j)
      d4[j] = rstd * acc[j] - rstd * muv * av[j] + bv[j] +
              ax[j] * x + ay[j] * y + c0[j] + m8r2;
    float o4[4];
    #pragma unroll
    for (int j = 0; j < 4; ++j) o4[j] = __shfl_xor(d4[j], 16);
    float mx = fmaxf(fmaxf(fmaxf(d4[0], d4[1]), fmaxf(d4[2], d4[3])),
                     fmaxf(fmaxf(o4[0], o4[1]), fmaxf(o4[2], o4[3])));
    float e4[4];
    float sum = 0.f;
    #pragma unroll
    for (int j = 0; j < 4; ++j) { e4[j] = __expf(d4[j] - mx); sum += e4[j]; }
    #pragma unroll
    for (int j = 0; j < 4; ++j) sum += __expf(o4[j] - mx);
    float inv = 1.f / sum;
    if (l4 < 2) {
      int tl = tile * 16 + l15;
      #pragma unroll
      for (int j = 0; j < 4; ++j) {
        float a = e4[j] * inv;
        u16 wr = f2bf(a * rstd);
        int s = l4 * 4 + j;
        *(u16*)((char*)attn_lds + ((s * 512 + tl * 2) ^ ((s & 7) << 4))) = wr;
        pa[j] += a; px[j] += a * x; py[j] += a * y;
        pg[j] += bf2f(wr) * muv;
      }
    }
  }
  #pragma unroll
  for (int m = 1; m < 16; m <<= 1) {
    #pragma unroll
    for (int j = 0; j < 4; ++j) {
      pa[j] += __shfl_xor(pa[j], m);
      px[j] += __shfl_xor(px[j], m);
      py[j] += __shfl_xor(py[j], m);
      pg[j] += __shfl_xor(pg[j], m);
    }
  }
  if (l15 == 0 && l4 < 2) {
    #pragma unroll
    for (int j = 0; j < 4; ++j) {
      int s = l4 * 4 + j;
      atomicAdd(&scal_cur[(b * 8 + s) * 4], pa[j]);
      atomicAdd(&scal_cur[(b * 8 + s) * 4 + 1], px[j]);
      atomicAdd(&scal_cur[(b * 8 + s) * 4 + 2], py[j]);
      atomicAdd(&scal_cur[(b * 8 + s) * 4 + 3], pg[j]);
    }
  }
  __syncthreads();
  int g32base = chunk >> 5;
  #pragma unroll
  for (int ni = 0; ni < 3; ++ni) {
    int nt = w * 3 + ni;
    f32x4 acc = (f32x4){0.f, 0.f, 0.f, 0.f};
    const u16* vp = fd + ((((long)b * 128 + g32base) * 12 + nt) * 64 + l4 * 16 + l15) * 8;
    #pragma unroll
    for (int gl = 0; gl < 8; ++gl) {
      int tl0 = gl * 32 + l4 * 8;
      bf16x8 afr = *(bf16x8*)((char*)attn_lds + ((l15 * 512 + tl0 * 2) ^ ((l15 & 7) << 4)));
      bf16x8 bfr = *(const bf16x8*)(vp + gl * 12 * 64 * 8);
      acc = __builtin_amdgcn_mfma_f32_16x16x32_bf16(afr, bfr, acc, 0, 0, 0);
    }
    if (l4 < 2) {
      #pragma unroll
      for (int j = 0; j < 4; ++j) {
        int s = l4 * 4 + j;
        atomicAdd(&U[((long)b * 8 + s) * DD + nt * 16 + l15], acc[j]);
      }
    }
  }
}

// ---------------------------------------------------------------------------
// GRU + LN + MLP.  768 threads; first phase computes
// upd = ((U - gamma) @ Wvm + asum*s0v) / (asum+eps).
// ---------------------------------------------------------------------------
template <int M>
__device__ void gru_body(int b0, int g, int srow,
                         float* u_l, float* h_l, float* gi_l, float* gh_l,
                         float* hn_l, float* ln_l, float* x1_l, float* out_l, float* st,
                         const float* __restrict__ U, const float* __restrict__ scal,
                         const float* __restrict__ Wvm, const float* __restrict__ s0v,
                         const float* __restrict__ sin_,
                         const u16* __restrict__ pWih, const u16* __restrict__ pWhh,
                         const float* __restrict__ bih, const float* __restrict__ bhh,
                         const float* __restrict__ mlng, const float* __restrict__ mlnb,
                         const u16* __restrict__ pW1, const float* __restrict__ b1,
                         const u16* __restrict__ pW2, const float* __restrict__ b2,
                         float* __restrict__ sout) {
  int tid = threadIdx.x;
  for (int idx = tid; idx < M * 192; idx += 768) {
    int row = idx / 192, d = idx % 192;
    int gr = b0 * 8 + srow + row;
    hn_l[row * 192 + d] = U[(long)gr * DD + d];
    h_l[row * 192 + d] = sin_[gr * DD + d];
  }
  __syncthreads();
  if (tid < M * 192) {
    int row = tid / 192, d = tid % 192;
    int gr = b0 * 8 + srow + row;
    float asum = scal[gr * 4], gam = scal[gr * 4 + 3];
    float inv = 1.f / (asum + 1e-8f);
    float acc = asum * s0v[d];
    const float* ur = hn_l + row * 192;
    #pragma unroll 4
    for (int e = 0; e < DD; ++e) acc += (ur[e] - gam) * Wvm[e * DD + d];
    u_l[row * 192 + d] = acc * inv;
  }
  __syncthreads();
  if (tid < 576) {
    int c = tid;
    const u16* wih = pWih + (size_t)g * 96 * 1152 + c * 2;
    const u16* whh = pWhh + (size_t)g * 96 * 1152 + c * 2;
    float ai[M], ah[M];
    #pragma unroll
    for (int r = 0; r < M; ++r) { ai[r] = 0.f; ah[r] = 0.f; }
    #pragma unroll 4
    for (int e2 = 0; e2 < 96; ++e2) {
      u32 wi = *(const u32*)(wih + e2 * 1152);
      u32 wh = *(const u32*)(whh + e2 * 1152);
      float wi0 = bf2f(wi & 0xffffu), wi1 = bf2f(wi >> 16);
      float wh0 = bf2f(wh & 0xffffu), wh1 = bf2f(wh >> 16);
      #pragma unroll
      for (int r = 0; r < M; ++r) {
        ai[r] += wi0 * u_l[r * 192 + e2 * 2] + wi1 * u_l[r * 192 + e2 * 2 + 1];
        ah[r] += wh0 * h_l[r * 192 + e2 * 2] + wh1 * h_l[r * 192 + e2 * 2 + 1];
      }
    }
    #pragma unroll
    for (int r = 0; r < M; ++r) { gi_l[r * 576 + c] = ai[r]; gh_l[r * 576 + c] = ah[r]; }
  }
  __syncthreads();
  if (tid < M * 192) {
    int row = tid / 192, uu = tid % 192;
    const float* bihg = bih + g * 576;
    const float* bhhg = bhh + g * 576;
    float r_ = sigm(gi_l[row * 576 + uu] + bihg[uu] + gh_l[row * 576 + uu] + bhhg[uu]);
    float z_ = sigm(gi_l[row * 576 + 192 + uu] + bihg[192 + uu] +
                    gh_l[row * 576 + 192 + uu] + bhhg[192 + uu]);
    float nn = gi_l[row * 576 + 384 + uu] + bihg[384 + uu] +
               r_ * (gh_l[row * 576 + 384 + uu] + bhhg[384 + uu]);
    float t = 1.f - 2.f / (__expf(2.f * nn) + 1.f);
    hn_l[row * 192 + uu] = (1.f - z_) * t + z_ * h_l[row * 192 + uu];
  }
  __syncthreads();
  {
    int wv = tid >> 6, lane = tid & 63;
    if (wv < M) {
      float v0 = hn_l[wv * 192 + lane], v1 = hn_l[wv * 192 + lane + 64],
            v2 = hn_l[wv * 192 + lane + 128];
      float s = v0 + v1 + v2, sq = v0 * v0 + v1 * v1 + v2 * v2;
      #pragma unroll
      for (int m = 1; m < 64; m <<= 1) { s += __shfl_xor(s, m); sq += __shfl_xor(sq, m); }
      if (lane == 0) {
        float mu = s * (1.f / 192.f);
        st[wv * 2] = mu;
        st[wv * 2 + 1] = rsqrtf(sq * (1.f / 192.f) - mu * mu + 1e-5f);
      }
    }
  }
  __syncthreads();
  if (tid < M * 192) {
    int row = tid / 192, uu = tid % 192;
    ln_l[row * 192 + uu] = (hn_l[row * 192 + uu] - st[row * 2]) * st[row * 2 + 1] *
                               mlng[g * DD + uu] + mlnb[g * DD + uu];
  }
  __syncthreads();
  {
    int c = tid;
    const u16* w1 = pW1 + (size_t)g * 96 * 1536 + c * 2;
    float a[M];
    #pragma unroll
    for (int r = 0; r < M; ++r) a[r] = 0.f;
    #pragma unroll 4
    for (int e2 = 0; e2 < 96; ++e2) {
      u32 wp = *(const u32*)(w1 + e2 * 1536);
      float w0 = bf2f(wp & 0xffffu), w1f = bf2f(wp >> 16);
      #pragma unroll
      for (int r = 0; r < M; ++r)
        a[r] += w0 * ln_l[r * 192 + e2 * 2] + w1f * ln_l[r * 192 + e2 * 2 + 1];
    }
    float bc = b1[g * HH + c];
    #pragma unroll
    for (int r = 0; r < M; ++r) x1_l[r * 768 + c] = fmaxf(a[r] + bc, 0.f);
  }
  if (tid < M * 192) {
    int row = tid / 192, uu = tid % 192;
    out_l[row * 192 + uu] = hn_l[row * 192 + uu] + b2[g * DD + uu];
  }
  __syncthreads();
  {
    int c = tid % 192, ks = tid / 192;
    const u16* w2 = pW2 + (size_t)g * 384 * 384 + c * 2;
    float a[M];
    #pragma unroll
    for (int r = 0; r < M; ++r) a[r] = 0.f;
    #pragma unroll 4
    for (int e2 = ks * 96; e2 < ks * 96 + 96; ++e2) {
      u32 wp = *(const u32*)(w2 + e2 * 384);
      float w0 = bf2f(wp & 0xffffu), w1f = bf2f(wp >> 16);
      #pragma unroll
      for (int r = 0; r < M; ++r)
        a[r] += w0 * x1_l[r * 768 + e2 * 2] + w1f * x1_l[r * 768 + e2 * 2 + 1];
    }
    #pragma unroll
    for (int r = 0; r < M; ++r) atomicAdd(&out_l[r * 192 + c], a[r]);
  }
  __syncthreads();
  if (tid < M * 192) {
    int row = tid / 192, d = tid % 192;
    sout[(b0 * 8 + srow + row) * DD + d] = out_l[row * 192 + d];
  }
}

__global__ __launch_bounds__(768) void gru_kernel(
    const float* __restrict__ U, const float* __restrict__ scal,
    const float* __restrict__ Wvm, const float* __restrict__ s0v,
    const float* __restrict__ sin_,
    const u16* __restrict__ pWih, const u16* __restrict__ pWhh,
    const float* __restrict__ bih, const float* __restrict__ bhh,
    const float* __restrict__ mlng, const float* __restrict__ mlnb,
    const u16* __restrict__ pW1, const float* __restrict__ b1,
    const u16* __restrict__ pW2, const float* __restrict__ b2,
    float* __restrict__ sout) {
  __shared__ float u_l[3 * 192], h_l[3 * 192], gi_l[3 * 576], gh_l[3 * 576];
  __shared__ float hn_l[3 * 192], ln_l[3 * 192], x1_l[3 * 768], out_l[3 * 192], st[8];
  int b = blockIdx.x, y = blockIdx.y;
  if (y == 0)
    gru_body<1>(b, 0, 0, u_l, h_l, gi_l, gh_l, hn_l, ln_l, x1_l, out_l, st,
                U, scal, Wvm, s0v, sin_, pWih, pWhh, bih, bhh, mlng, mlnb,
                pW1, b1, pW2, b2, sout);
  else if (y == 1)
    gru_body<1>(b, 2, 7, u_l, h_l, gi_l, gh_l, hn_l, ln_l, x1_l, out_l, st,
                U, scal, Wvm, s0v, sin_, pWih, pWhh, bih, bhh, mlng, mlnb,
                pW1, b1, pW2, b2, sout);
  else if (y == 2)
    gru_body<3>(b, 1, 1, u_l, h_l, gi_l, gh_l, hn_l, ln_l, x1_l, out_l, st,
                U, scal, Wvm, s0v, sin_, pWih, pWhh, bih, bhh, mlng, mlnb,
                pW1, b1, pW2, b2, sout);
  else
    gru_body<3>(b, 1, 4, u_l, h_l, gi_l, gh_l, hn_l, ln_l, x1_l, out_l, st,
                U, scal, Wvm, s0v, sin_, pWih, pWhh, bih, bhh, mlng, mlnb,
                pW1, b1, pW2, b2, sout);
}

// ---------------------------------------------------------------------------
extern "C" void kernel_launch(void* const* d_in, const int* in_sizes, int n_in,
                              void* d_out, int out_size, void* d_ws, size_t ws_size,
                              hipStream_t stream) {
  const float* feat = (const float*)d_in[0];
  const float* slots = (const float*)d_in[1];
  const float* Wk = (const float*)d_in[2];
  const float* Wv = (const float*)d_in[3];
  const float* Wq = (const float*)d_in[4];
  const float* lfg = (const float*)d_in[5];
  const float* lfb = (const float*)d_in[6];
  const float* lsg = (const float*)d_in[7];
  const float* lsb = (const float*)d_in[8];
  const float* gWih = (const float*)d_in[9];
  const float* gWhh = (const float*)d_in[10];
  const float* gbih = (const float*)d_in[11];
  const float* gbhh = (const float*)d_in[12];
  const float* mlng = (const float*)d_in[13];
  const float* mlnb = (const float*)d_in[14];
  const float* W1 = (const float*)d_in[15];
  const float* b1 = (const float*)d_in[16];
  const float* W2 = (const float*)d_in[17];
  const float* b2 = (const float*)d_in[18];
  float* out = (float*)d_out;

  char* ws = (char*)d_ws;
  size_t off = 0;
  auto alloc = [&](size_t bytes) {
    void* p = ws + off;
    off += (bytes + 255) & ~(size_t)255;
    return p;
  };
  u16* fb      = (u16*)alloc((size_t)BB * FF * DD * 2);
  u16* fd      = (u16*)alloc((size_t)BB * DD * FF * 2);
  float2* stats = (float2*)alloc((size_t)BB * FF * 8);
  u16* pbuf    = (u16*)alloc((size_t)BB * 16 * DD * 2);
  float* pab   = (float*)alloc((size_t)BB * 8 * 2 * 4);
  float* U     = (float*)alloc((size_t)BB * 8 * DD * 4);
  float* slA   = (float*)alloc((size_t)BB * 8 * DD * 4);
  float* slB   = (float*)alloc((size_t)BB * 8 * DD * 4);
  float* scal0 = (float*)alloc(BB * 8 * 4 * 4);
  float* scal1 = (float*)alloc(BB * 8 * 4 * 4);
  float* Wvm   = (float*)alloc((size_t)DD * DD * 4);
  float* s0v   = (float*)alloc(DD * 4);
  float* s0k   = (float*)alloc(DD * 4);
  u16* pWih    = (u16*)alloc((size_t)3 * 576 * DD * 2);
  u16* pWhh    = (u16*)alloc((size_t)3 * 576 * DD * 2);
  u16* pW1     = (u16*)alloc((size_t)3 * DD * HH * 2);
  u16* pW2     = (u16*)alloc((size_t)3 * HH * DD * 2);

  prep_vw<<<1, 192, 0, stream>>>(Wk, Wv, lfg, lfb, Wvm, s0v, s0k);
  prep_packw<<<dim3(432, 4), 256, 0, stream>>>(gWih, gWhh, W1, W2, pWih, pWhh, pW1, pW2);

  float* souts[3] = {slA, slB, out};
  float* scals[2] = {scal0, scal1};

  // iteration 0: qproj from input slots, then fused fconv+attn, then gru
  qproj_kernel<<<BB * 8, 64, 0, stream>>>(slots, Wq, lsg, lsb, Wk, lfg, s0k,
                                          pbuf, pab, U, scals[0]);
  fconv_attn1<<<BB * FF / 64, 256, 0, stream>>>(feat, fb, fd, stats, pbuf, pab,
                                                U, scals[0]);
  gru_kernel<<<dim3(BB, 4), 768, 0, stream>>>(U, scals[0], Wvm, s0v, slots,
                                              pWih, pWhh, gbih, gbhh, mlng, mlnb,
                                              pW1, b1, pW2, b2, souts[0]);
  const float* sin_ = souts[0];
  for (int it = 1; it < 3; ++it) {
    int cur = it & 1, prev = cur ^ 1;
    qproj_kernel<<<BB * 8, 64, 0, stream>>>(sin_, Wq, lsg, lsb, Wk, lfg, s0k,
                                            pbuf, pab, U, scals[cur]);
    attnpv_kernel<<<dim3(BB, 16), 256, 0, stream>>>(fb, fd, pbuf, pab, stats,
                                                    scals[prev], U, scals[cur]);
    gru_kernel<<<dim3(BB, 4), 768, 0, stream>>>(U, scals[cur], Wvm, s0v, sin_,
                                                pWih, pWhh, gbih, gbhh, mlng, mlnb,
                                                pW1, b1, pW2, b2, souts[it]);
    sin_ = souts[it];
  }
}

// Round 9
// 605.033 us; speedup vs baseline: 1.2805x; 1.2805x over previous
//
#include <hip/hip_runtime.h>

typedef unsigned short u16;
typedef unsigned int u32;

#define BB 64
#define FF 4096
#define DD 192
#define HH 768

typedef __attribute__((ext_vector_type(8))) __bf16 bf16x8;
typedef __attribute__((ext_vector_type(4))) float f32x4;

__device__ __forceinline__ float bf2f(u32 u) {
  union { u32 i; float f; } x; x.i = u << 16; return x.f;
}
__device__ __forceinline__ u16 f2bf(float f) {
  __bf16 h = (__bf16)f;
  return __builtin_bit_cast(u16, h);
}
__device__ __forceinline__ u32 pk2bf(float a, float b) {
  return (u32)f2bf(a) | ((u32)f2bf(b) << 16);
}
__device__ __forceinline__ float sigm(float x) { return 1.f / (1.f + __expf(-x)); }

// ---------------------------------------------------------------------------
// Prep: Wvm[e][d] = g[e]*Wv[e][d] (f32), s0v[d] = b@Wv, s0k[d] = b@Wk.
// ---------------------------------------------------------------------------
__global__ void prep_vw(const float* __restrict__ Wk, const float* __restrict__ Wv,
                        const float* __restrict__ g, const float* __restrict__ bb,
                        float* __restrict__ Wvm, float* __restrict__ s0v,
                        float* __restrict__ s0k) {
  int d = threadIdx.x;  // 0..191
  float av = 0.f, ak = 0.f;
  for (int e = 0; e < DD; ++e) {
    float wv = Wv[e * DD + d];
    Wvm[e * DD + d] = g[e] * wv;
    av += bb[e] * wv;
    ak += bb[e] * Wk[e * DD + d];
  }
  s0v[d] = av; s0k[d] = ak;
}

// Pack GRU/MLP weights to bf16 e-pairs: dst[((g*E2+e/2)*N + n)*2 + (e&1)].
__global__ void prep_packw(const float* __restrict__ Wih, const float* __restrict__ Whh,
                           const float* __restrict__ W1, const float* __restrict__ W2,
                           u16* __restrict__ pWih, u16* __restrict__ pWhh,
                           u16* __restrict__ pW1, u16* __restrict__ pW2) {
  int which = blockIdx.y;
  int total, N, E;
  const float* src; u16* dst; int srcEmajor;
  if (which < 2) { total = 3 * 576 * 192; N = 576; E = 192; srcEmajor = 0;
                   src = which ? Whh : Wih; dst = which ? pWhh : pWih; }
  else if (which == 2) { total = 3 * 192 * 768; N = 768; E = 192; srcEmajor = 1;
                         src = W1; dst = pW1; }
  else { total = 3 * 768 * 192; N = 192; E = 768; srcEmajor = 1; src = W2; dst = pW2; }
  for (int idx = blockIdx.x * 256 + threadIdx.x; idx < total; idx += gridDim.x * 256) {
    int g = idx / (N * E), rem = idx % (N * E);
    int n, e;
    if (srcEmajor) { e = rem / N; n = rem % N; }    // src[g][e][n]
    else { n = rem / E; e = rem % E; }              // src[g][n][e]
    dst[((g * (E / 2) + (e >> 1)) * N + n) * 2 + (e & 1)] = f2bf(src[idx]);
  }
}

// ---------------------------------------------------------------------------
// fconv: stream feat f32 -> bf16 in two layouts + per-token LN stats.
// fb: QK granules [Tg][u(24)][tau16][8dims].  fd: PV granules
// [((b*128+g32)*12+ntg)*64 + l4f*16 + (d&15)][8toks].  stats[t]={rstd, mu}.
// ---------------------------------------------------------------------------
__global__ __launch_bounds__(256) void fconv(const float* __restrict__ feat,
                                             u16* __restrict__ fb, u16* __restrict__ fd,
                                             float2* __restrict__ stats) {
  __shared__ __align__(16) u16 flds[64 * 192];   // token-major bf16 tile
  int tid = threadIdx.x;
  int blk = blockIdx.x;
  int r = tid >> 2, p = tid & 3;
  long t = (long)blk * 64 + r;
  const float4* src = (const float4*)(feat + t * DD) + p * 12;
  float s = 0.f, s2 = 0.f;
  long Tg = t >> 4; int tau = (int)(t & 15);
  #pragma unroll
  for (int i = 0; i < 6; ++i) {
    float4 a = src[i * 2], b = src[i * 2 + 1];
    s += a.x + a.y + a.z + a.w + b.x + b.y + b.z + b.w;
    s2 += a.x * a.x + a.y * a.y + a.z * a.z + a.w * a.w +
          b.x * b.x + b.y * b.y + b.z * b.z + b.w * b.w;
    uint4 v;
    v.x = pk2bf(a.x, a.y); v.y = pk2bf(a.z, a.w);
    v.z = pk2bf(b.x, b.y); v.w = pk2bf(b.z, b.w);
    int u = p * 6 + i;
    *(uint4*)(fb + ((Tg * 24 + u) * 16 + tau) * 8) = v;
    *(uint4*)((char*)flds + r * 384 + p * 96 + i * 16) = v;
  }
  s += __shfl_xor(s, 1); s2 += __shfl_xor(s2, 1);
  s += __shfl_xor(s, 2); s2 += __shfl_xor(s2, 2);
  if (p == 0) {
    float mu = s * (1.f / 192.f);
    float rstd = rsqrtf(s2 * (1.f / 192.f) - mu * mu + 1e-5f);
    stats[t] = make_float2(rstd, mu);
  }
  __syncthreads();
  // fd pass: granule = (8 tokens, 1 dim).  idx -> (tg8 = token-octet, d).
  int b = blk >> 6;
  #pragma unroll
  for (int i = 0; i < 6; ++i) {
    int idx = tid + i * 256;            // 0..1535
    int tg8 = idx / 192, d = idx % 192;
    u16 h[8];
    #pragma unroll
    for (int j = 0; j < 8; ++j) h[j] = flds[(tg8 * 8 + j) * 192 + d];
    uint4 v;
    v.x = (u32)h[0] | ((u32)h[1] << 16);
    v.y = (u32)h[2] | ((u32)h[3] << 16);
    v.z = (u32)h[4] | ((u32)h[5] << 16);
    v.w = (u32)h[6] | ((u32)h[7] << 16);
    int g32 = (blk & 63) * 2 + (tg8 >> 2);
    int l4f = tg8 & 3;
    *(uint4*)(fd + ((((long)b * 128 + g32) * 12 + (d >> 4)) * 64 + l4f * 16 +
                    (d & 15)) * 8) = v;
  }
}

// ---------------------------------------------------------------------------
// q projection + p = g ⊙ (Wk @ q), alpha = sum(bf16(p)), beta = s0k·q.
// One wave per (b,slot).  Also zeroes U/scal_cur and pbuf rows 8..15.
// ---------------------------------------------------------------------------
__global__ __launch_bounds__(64) void qproj_kernel(
    const float* __restrict__ slots, const float* __restrict__ Wq,
    const float* __restrict__ lsg, const float* __restrict__ lsb,
    const float* __restrict__ Wk, const float* __restrict__ lfg,
    const float* __restrict__ s0k,
    u16* __restrict__ pbuf, float* __restrict__ pab,
    float* __restrict__ U, float* __restrict__ scal_cur) {
  __shared__ float ln[192];
  int bk = blockIdx.x;
  int b = bk >> 3, sl = bk & 7;
  int lane = threadIdx.x;
  {
    int gtid = bk * 64 + lane;
    float4 z = {0.f, 0.f, 0.f, 0.f};
    if (gtid < 24576) ((float4*)U)[gtid] = z;
    else if (gtid < 24576 + 512) ((float4*)scal_cur)[gtid - 24576] = z;
  }
  const float* x = slots + bk * DD;
  float v0 = x[lane], v1 = x[lane + 64], v2 = x[lane + 128];
  float s = v0 + v1 + v2, s2 = v0 * v0 + v1 * v1 + v2 * v2;
  #pragma unroll
  for (int m = 1; m < 64; m <<= 1) { s += __shfl_xor(s, m); s2 += __shfl_xor(s2, m); }
  float mu = s * (1.f / 192.f);
  float rstd = rsqrtf(s2 * (1.f / 192.f) - mu * mu + 1e-5f);
  ln[lane]       = (v0 - mu) * rstd * lsg[lane]       + lsb[lane];
  ln[lane + 64]  = (v1 - mu) * rstd * lsg[lane + 64]  + lsb[lane + 64];
  ln[lane + 128] = (v2 - mu) * rstd * lsg[lane + 128] + lsb[lane + 128];
  __syncthreads();
  float a0 = 0.f, a1 = 0.f, a2 = 0.f;
  for (int e = 0; e < DD; ++e) {
    float le = ln[e];
    a0 += le * Wq[e * DD + lane];
    a1 += le * Wq[e * DD + lane + 64];
    a2 += le * Wq[e * DD + lane + 128];
  }
  __syncthreads();
  const float scale = 0.07216878364870323f;  // 192^-0.5
  ln[lane] = a0 * scale; ln[lane + 64] = a1 * scale; ln[lane + 128] = a2 * scale;
  __syncthreads();
  float al = 0.f, be = 0.f;
  u16 pb[3];
  #pragma unroll
  for (int k3 = 0; k3 < 3; ++k3) {
    int d = lane + k3 * 64;
    const float* wr = Wk + (size_t)d * DD;
    float pd = 0.f;
    for (int e = 0; e < DD; ++e) pd += wr[e] * ln[e];
    pd *= lfg[d];
    u16 h = f2bf(pd);
    pb[k3] = h;
    al += bf2f(h);
    be += s0k[d] * ln[d];
  }
  #pragma unroll
  for (int m = 1; m < 64; m <<= 1) { al += __shfl_xor(al, m); be += __shfl_xor(be, m); }
  #pragma unroll
  for (int k3 = 0; k3 < 3; ++k3)
    pbuf[(b * 16 + sl) * DD + lane + k3 * 64] = pb[k3];
  if (lane < 24) *(uint4*)(pbuf + (b * 16 + 8 + sl) * DD + lane * 8) = (uint4){0, 0, 0, 0};
  if (lane == 0) { pab[bk * 2] = al; pab[bk * 2 + 1] = be; }
}

// ---------------------------------------------------------------------------
// Fused attention + update on raw features:
// dots = rstd*(f.p) - rstd*mu*alpha + beta (+bias) -> softmax over 8 ->
// w' = attn*rstd to LDS -> PV MFMA (U += w' f) -> atomics.
// grid (B, 32): 128 tokens per block (8 blocks/CU for latency hiding).
// ---------------------------------------------------------------------------
__global__ __launch_bounds__(256) void attnpv_kernel(
    const u16* __restrict__ fb, const u16* __restrict__ fd,
    const u16* __restrict__ pbuf, const float* __restrict__ pab,
    const float2* __restrict__ stats,
    const float* __restrict__ scal_prev,
    float* __restrict__ U, float* __restrict__ scal_cur, int have_bias) {
  __shared__ __align__(16) u16 plds[16 * 192];
  __shared__ __align__(16) u16 attn_lds[16 * 128];   // [slot][token], XOR-swizzled
  int b = blockIdx.x;
  int chunk = blockIdx.y * 128;
  int tid = threadIdx.x;
  #pragma unroll
  for (int i = 0; i < 2; ++i) {
    int g = tid + i * 256;
    if (g < 384) {
      int s = g / 24, u = g % 24;
      uint4 v = *(const uint4*)(pbuf + ((b * 16 + s) * DD + u * 8));
      *(uint4*)((char*)plds + s * 384 + ((u ^ (s & 7)) << 4)) = v;
    }
  }
  if (tid < 128) *(uint4*)((char*)attn_lds + 2048 + tid * 16) = (uint4){0, 0, 0, 0};
  __syncthreads();
  int w = tid >> 6, lane = tid & 63;
  int l15 = lane & 15, l4 = lane >> 4;
  bf16x8 qfr[6];
  #pragma unroll
  for (int kk = 0; kk < 6; ++kk) {
    int u = kk * 4 + l4;
    qfr[kk] = *(bf16x8*)((char*)plds + l15 * 384 + ((u ^ (l15 & 7)) << 4));
  }
  float ax[4], ay[4], c0[4], av[4], bv[4];
  #pragma unroll
  for (int j = 0; j < 4; ++j) {
    int s = l4 * 4 + j;
    if (s < 8) {
      av[j] = pab[(b * 8 + s) * 2];
      bv[j] = pab[(b * 8 + s) * 2 + 1];
      if (have_bias) {
        float inv = 1.f / (scal_prev[(b * 8 + s) * 4] + 1e-8f);
        float cx = scal_prev[(b * 8 + s) * 4 + 1] * inv;
        float cy = scal_prev[(b * 8 + s) * 4 + 2] * inv;
        ax[j] = 16.f * cx; ay[j] = 16.f * cy; c0[j] = -8.f * (cx * cx + cy * cy);
      } else { ax[j] = 0.f; ay[j] = 0.f; c0[j] = 0.f; }
    } else { av[j] = 0.f; bv[j] = 0.f; ax[j] = 0.f; ay[j] = 0.f; c0[j] = 0.f; }
  }
  float pa[4], px[4], py[4], pg[4];
  #pragma unroll
  for (int j = 0; j < 4; ++j) { pa[j] = 0.f; px[j] = 0.f; py[j] = 0.f; pg[j] = 0.f; }
  #pragma unroll
  for (int tile = w; tile < 8; tile += 4) {
    int t0 = chunk + tile * 16;
    long Tg = (long)b * 256 + (t0 >> 4);
    const u16* kp = fb + (Tg * 24 + l4) * 128 + l15 * 8;
    f32x4 acc = (f32x4){0.f, 0.f, 0.f, 0.f};
    #pragma unroll
    for (int kk = 0; kk < 6; ++kk) {
      bf16x8 bfr = *(const bf16x8*)(kp + kk * 512);
      acc = __builtin_amdgcn_mfma_f32_16x16x32_bf16(qfr[kk], bfr, acc, 0, 0, 0);
    }
    int t = t0 + l15;
    float2 st = stats[((long)b << 12) + t];
    float rstd = st.x, muv = st.y;
    float x = -1.f + (float)(t & 63) * (2.f / 63.f);
    float y = -1.f + (float)(t >> 6) * (2.f / 63.f);
    float m8r2 = -8.f * (x * x + y * y);
    float d4[4];
    #pragma unroll
    for (int j = 0; j < 4; ++j)
      d4[j] = rstd * acc[j] - rstd * muv * av[j] + bv[j] +
              (have_bias ? (ax[j] * x + ay[j] * y + c0[j] + m8r2) : 0.f);
    float o4[4];
    #pragma unroll
    for (int j = 0; j < 4; ++j) o4[j] = __shfl_xor(d4[j], 16);
    float mx = fmaxf(fmaxf(fmaxf(d4[0], d4[1]), fmaxf(d4[2], d4[3])),
                     fmaxf(fmaxf(o4[0], o4[1]), fmaxf(o4[2], o4[3])));
    float e4[4];
    float sum = 0.f;
    #pragma unroll
    for (int j = 0; j < 4; ++j) { e4[j] = __expf(d4[j] - mx); sum += e4[j]; }
    #pragma unroll
    for (int j = 0; j < 4; ++j) sum += __expf(o4[j] - mx);
    float inv = 1.f / sum;
    if (l4 < 2) {
      int tl = tile * 16 + l15;
      #pragma unroll
      for (int j = 0; j < 4; ++j) {
        float a = e4[j] * inv;
        u16 wr = f2bf(a * rstd);
        int s = l4 * 4 + j;
        *(u16*)((char*)attn_lds + ((s * 256 + tl * 2) ^ ((s & 7) << 4))) = wr;
        pa[j] += a; px[j] += a * x; py[j] += a * y;
        pg[j] += bf2f(wr) * muv;
      }
    }
  }
  #pragma unroll
  for (int m = 1; m < 16; m <<= 1) {
    #pragma unroll
    for (int j = 0; j < 4; ++j) {
      pa[j] += __shfl_xor(pa[j], m);
      px[j] += __shfl_xor(px[j], m);
      py[j] += __shfl_xor(py[j], m);
      pg[j] += __shfl_xor(pg[j], m);
    }
  }
  if (l15 == 0 && l4 < 2) {
    #pragma unroll
    for (int j = 0; j < 4; ++j) {
      int s = l4 * 4 + j;
      atomicAdd(&scal_cur[(b * 8 + s) * 4], pa[j]);
      atomicAdd(&scal_cur[(b * 8 + s) * 4 + 1], px[j]);
      atomicAdd(&scal_cur[(b * 8 + s) * 4 + 2], py[j]);
      atomicAdd(&scal_cur[(b * 8 + s) * 4 + 3], pg[j]);
    }
  }
  __syncthreads();
  // ---- PV: U[slot][dim] += sum_t w'[slot][t] * f[t][dim] (K = 128) ----
  int g32base = chunk >> 5;
  #pragma unroll
  for (int ni = 0; ni < 3; ++ni) {
    int nt = w * 3 + ni;
    f32x4 acc = (f32x4){0.f, 0.f, 0.f, 0.f};
    const u16* vp = fd + ((((long)b * 128 + g32base) * 12 + nt) * 64 + l4 * 16 + l15) * 8;
    #pragma unroll
    for (int gl = 0; gl < 4; ++gl) {
      int tl0 = gl * 32 + l4 * 8;
      bf16x8 afr = *(bf16x8*)((char*)attn_lds + ((l15 * 256 + tl0 * 2) ^ ((l15 & 7) << 4)));
      bf16x8 bfr = *(const bf16x8*)(vp + gl * 12 * 64 * 8);
      acc = __builtin_amdgcn_mfma_f32_16x16x32_bf16(afr, bfr, acc, 0, 0, 0);
    }
    if (l4 < 2) {
      #pragma unroll
      for (int j = 0; j < 4; ++j) {
        int s = l4 * 4 + j;
        atomicAdd(&U[((long)b * 8 + s) * DD + nt * 16 + l15], acc[j]);
      }
    }
  }
}

// ---------------------------------------------------------------------------
// GRU + LN + MLP.  768 threads; first phase computes
// upd = ((U - gamma) @ Wvm + asum*s0v) / (asum+eps).
// ---------------------------------------------------------------------------
template <int M>
__device__ void gru_body(int b0, int g, int srow,
                         float* u_l, float* h_l, float* gi_l, float* gh_l,
                         float* hn_l, float* ln_l, float* x1_l, float* out_l, float* st,
                         const float* __restrict__ U, const float* __restrict__ scal,
                         const float* __restrict__ Wvm, const float* __restrict__ s0v,
                         const float* __restrict__ sin_,
                         const u16* __restrict__ pWih, const u16* __restrict__ pWhh,
                         const float* __restrict__ bih, const float* __restrict__ bhh,
                         const float* __restrict__ mlng, const float* __restrict__ mlnb,
                         const u16* __restrict__ pW1, const float* __restrict__ b1,
                         const u16* __restrict__ pW2, const float* __restrict__ b2,
                         float* __restrict__ sout) {
  int tid = threadIdx.x;
  for (int idx = tid; idx < M * 192; idx += 768) {
    int row = idx / 192, d = idx % 192;
    int gr = b0 * 8 + srow + row;
    hn_l[row * 192 + d] = U[(long)gr * DD + d];
    h_l[row * 192 + d] = sin_[gr * DD + d];
  }
  __syncthreads();
  if (tid < M * 192) {
    int row = tid / 192, d = tid % 192;
    int gr = b0 * 8 + srow + row;
    float asum = scal[gr * 4], gam = scal[gr * 4 + 3];
    float inv = 1.f / (asum + 1e-8f);
    float acc = asum * s0v[d];
    const float* ur = hn_l + row * 192;
    #pragma unroll 4
    for (int e = 0; e < DD; ++e) acc += (ur[e] - gam) * Wvm[e * DD + d];
    u_l[row * 192 + d] = acc * inv;
  }
  __syncthreads();
  if (tid < 576) {
    int c = tid;
    const u16* wih = pWih + (size_t)g * 96 * 1152 + c * 2;
    const u16* whh = pWhh + (size_t)g * 96 * 1152 + c * 2;
    float ai[M], ah[M];
    #pragma unroll
    for (int r = 0; r < M; ++r) { ai[r] = 0.f; ah[r] = 0.f; }
    #pragma unroll 4
    for (int e2 = 0; e2 < 96; ++e2) {
      u32 wi = *(const u32*)(wih + e2 * 1152);
      u32 wh = *(const u32*)(whh + e2 * 1152);
      float wi0 = bf2f(wi & 0xffffu), wi1 = bf2f(wi >> 16);
      float wh0 = bf2f(wh & 0xffffu), wh1 = bf2f(wh >> 16);
      #pragma unroll
      for (int r = 0; r < M; ++r) {
        ai[r] += wi0 * u_l[r * 192 + e2 * 2] + wi1 * u_l[r * 192 + e2 * 2 + 1];
        ah[r] += wh0 * h_l[r * 192 + e2 * 2] + wh1 * h_l[r * 192 + e2 * 2 + 1];
      }
    }
    #pragma unroll
    for (int r = 0; r < M; ++r) { gi_l[r * 576 + c] = ai[r]; gh_l[r * 576 + c] = ah[r]; }
  }
  __syncthreads();
  if (tid < M * 192) {
    int row = tid / 192, uu = tid % 192;
    const float* bihg = bih + g * 576;
    const float* bhhg = bhh + g * 576;
    float r_ = sigm(gi_l[row * 576 + uu] + bihg[uu] + gh_l[row * 576 + uu] + bhhg[uu]);
    float z_ = sigm(gi_l[row * 576 + 192 + uu] + bihg[192 + uu] +
                    gh_l[row * 576 + 192 + uu] + bhhg[192 + uu]);
    float nn = gi_l[row * 576 + 384 + uu] + bihg[384 + uu] +
               r_ * (gh_l[row * 576 + 384 + uu] + bhhg[384 + uu]);
    float t = 1.f - 2.f / (__expf(2.f * nn) + 1.f);
    hn_l[row * 192 + uu] = (1.f - z_) * t + z_ * h_l[row * 192 + uu];
  }
  __syncthreads();
  {
    int wv = tid >> 6, lane = tid & 63;
    if (wv < M) {
      float v0 = hn_l[wv * 192 + lane], v1 = hn_l[wv * 192 + lane + 64],
            v2 = hn_l[wv * 192 + lane + 128];
      float s = v0 + v1 + v2, sq = v0 * v0 + v1 * v1 + v2 * v2;
      #pragma unroll
      for (int m = 1; m < 64; m <<= 1) { s += __shfl_xor(s, m); sq += __shfl_xor(sq, m); }
      if (lane == 0) {
        float mu = s * (1.f / 192.f);
        st[wv * 2] = mu;
        st[wv * 2 + 1] = rsqrtf(sq * (1.f / 192.f) - mu * mu + 1e-5f);
      }
    }
  }
  __syncthreads();
  if (tid < M * 192) {
    int row = tid / 192, uu = tid % 192;
    ln_l[row * 192 + uu] = (hn_l[row * 192 + uu] - st[row * 2]) * st[row * 2 + 1] *
                               mlng[g * DD + uu] + mlnb[g * DD + uu];
  }
  __syncthreads();
  {
    int c = tid;
    const u16* w1 = pW1 + (size_t)g * 96 * 1536 + c * 2;
    float a[M];
    #pragma unroll
    for (int r = 0; r < M; ++r) a[r] = 0.f;
    #pragma unroll 4
    for (int e2 = 0; e2 < 96; ++e2) {
      u32 wp = *(const u32*)(w1 + e2 * 1536);
      float w0 = bf2f(wp & 0xffffu), w1f = bf2f(wp >> 16);
      #pragma unroll
      for (int r = 0; r < M; ++r)
        a[r] += w0 * ln_l[r * 192 + e2 * 2] + w1f * ln_l[r * 192 + e2 * 2 + 1];
    }
    float bc = b1[g * HH + c];
    #pragma unroll
    for (int r = 0; r < M; ++r) x1_l[r * 768 + c] = fmaxf(a[r] + bc, 0.f);
  }
  if (tid < M * 192) {
    int row = tid / 192, uu = tid % 192;
    out_l[row * 192 + uu] = hn_l[row * 192 + uu] + b2[g * DD + uu];
  }
  __syncthreads();
  {
    int c = tid % 192, ks = tid / 192;
    const u16* w2 = pW2 + (size_t)g * 384 * 384 + c * 2;
    float a[M];
    #pragma unroll
    for (int r = 0; r < M; ++r) a[r] = 0.f;
    #pragma unroll 4
    for (int e2 = ks * 96; e2 < ks * 96 + 96; ++e2) {
      u32 wp = *(const u32*)(w2 + e2 * 384);
      float w0 = bf2f(wp & 0xffffu), w1f = bf2f(wp >> 16);
      #pragma unroll
      for (int r = 0; r < M; ++r)
        a[r] += w0 * x1_l[r * 768 + e2 * 2] + w1f * x1_l[r * 768 + e2 * 2 + 1];
    }
    #pragma unroll
    for (int r = 0; r < M; ++r) atomicAdd(&out_l[r * 192 + c], a[r]);
  }
  __syncthreads();
  if (tid < M * 192) {
    int row = tid / 192, d = tid % 192;
    sout[(b0 * 8 + srow + row) * DD + d] = out_l[row * 192 + d];
  }
}

__global__ __launch_bounds__(768) void gru_kernel(
    const float* __restrict__ U, const float* __restrict__ scal,
    const float* __restrict__ Wvm, const float* __restrict__ s0v,
    const float* __restrict__ sin_,
    const u16* __restrict__ pWih, const u16* __restrict__ pWhh,
    const float* __restrict__ bih, const float* __restrict__ bhh,
    const float* __restrict__ mlng, const float* __restrict__ mlnb,
    const u16* __restrict__ pW1, const float* __restrict__ b1,
    const u16* __restrict__ pW2, const float* __restrict__ b2,
    float* __restrict__ sout) {
  __shared__ float u_l[3 * 192], h_l[3 * 192], gi_l[3 * 576], gh_l[3 * 576];
  __shared__ float hn_l[3 * 192], ln_l[3 * 192], x1_l[3 * 768], out_l[3 * 192], st[8];
  int b = blockIdx.x, y = blockIdx.y;
  if (y == 0)
    gru_body<1>(b, 0, 0, u_l, h_l, gi_l, gh_l, hn_l, ln_l, x1_l, out_l, st,
                U, scal, Wvm, s0v, sin_, pWih, pWhh, bih, bhh, mlng, mlnb,
                pW1, b1, pW2, b2, sout);
  else if (y == 1)
    gru_body<1>(b, 2, 7, u_l, h_l, gi_l, gh_l, hn_l, ln_l, x1_l, out_l, st,
                U, scal, Wvm, s0v, sin_, pWih, pWhh, bih, bhh, mlng, mlnb,
                pW1, b1, pW2, b2, sout);
  else if (y == 2)
    gru_body<3>(b, 1, 1, u_l, h_l, gi_l, gh_l, hn_l, ln_l, x1_l, out_l, st,
                U, scal, Wvm, s0v, sin_, pWih, pWhh, bih, bhh, mlng, mlnb,
                pW1, b1, pW2, b2, sout);
  else
    gru_body<3>(b, 1, 4, u_l, h_l, gi_l, gh_l, hn_l, ln_l, x1_l, out_l, st,
                U, scal, Wvm, s0v, sin_, pWih, pWhh, bih, bhh, mlng, mlnb,
                pW1, b1, pW2, b2, sout);
}

// ---------------------------------------------------------------------------
extern "C" void kernel_launch(void* const* d_in, const int* in_sizes, int n_in,
                              void* d_out, int out_size, void* d_ws, size_t ws_size,
                              hipStream_t stream) {
  const float* feat = (const float*)d_in[0];
  const float* slots = (const float*)d_in[1];
  const float* Wk = (const float*)d_in[2];
  const float* Wv = (const float*)d_in[3];
  const float* Wq = (const float*)d_in[4];
  const float* lfg = (const float*)d_in[5];
  const float* lfb = (const float*)d_in[6];
  const float* lsg = (const float*)d_in[7];
  const float* lsb = (const float*)d_in[8];
  const float* gWih = (const float*)d_in[9];
  const float* gWhh = (const float*)d_in[10];
  const float* gbih = (const float*)d_in[11];
  const float* gbhh = (const float*)d_in[12];
  const float* mlng = (const float*)d_in[13];
  const float* mlnb = (const float*)d_in[14];
  const float* W1 = (const float*)d_in[15];
  const float* b1 = (const float*)d_in[16];
  const float* W2 = (const float*)d_in[17];
  const float* b2 = (const float*)d_in[18];
  float* out = (float*)d_out;

  char* ws = (char*)d_ws;
  size_t off = 0;
  auto alloc = [&](size_t bytes) {
    void* p = ws + off;
    off += (bytes + 255) & ~(size_t)255;
    return p;
  };
  u16* fb      = (u16*)alloc((size_t)BB * FF * DD * 2);
  u16* fd      = (u16*)alloc((size_t)BB * DD * FF * 2);
  float2* stats = (float2*)alloc((size_t)BB * FF * 8);
  u16* pbuf    = (u16*)alloc((size_t)BB * 16 * DD * 2);
  float* pab   = (float*)alloc((size_t)BB * 8 * 2 * 4);
  float* U     = (float*)alloc((size_t)BB * 8 * DD * 4);
  float* slA   = (float*)alloc((size_t)BB * 8 * DD * 4);
  float* slB   = (float*)alloc((size_t)BB * 8 * DD * 4);
  float* scal0 = (float*)alloc(BB * 8 * 4 * 4);
  float* scal1 = (float*)alloc(BB * 8 * 4 * 4);
  float* Wvm   = (float*)alloc((size_t)DD * DD * 4);
  float* s0v   = (float*)alloc(DD * 4);
  float* s0k   = (float*)alloc(DD * 4);
  u16* pWih    = (u16*)alloc((size_t)3 * 576 * DD * 2);
  u16* pWhh    = (u16*)alloc((size_t)3 * 576 * DD * 2);
  u16* pW1     = (u16*)alloc((size_t)3 * DD * HH * 2);
  u16* pW2     = (u16*)alloc((size_t)3 * HH * DD * 2);

  prep_vw<<<1, 192, 0, stream>>>(Wk, Wv, lfg, lfb, Wvm, s0v, s0k);
  prep_packw<<<dim3(432, 4), 256, 0, stream>>>(gWih, gWhh, W1, W2, pWih, pWhh, pW1, pW2);
  fconv<<<BB * FF / 64, 256, 0, stream>>>(feat, fb, fd, stats);

  const float* sin_ = slots;
  float* souts[3] = {slA, slB, out};
  float* scals[2] = {scal0, scal1};
  for (int it = 0; it < 3; ++it) {
    int cur = it & 1, prev = cur ^ 1;
    qproj_kernel<<<BB * 8, 64, 0, stream>>>(sin_, Wq, lsg, lsb, Wk, lfg, s0k,
                                            pbuf, pab, U, scals[cur]);
    attnpv_kernel<<<dim3(BB, 32), 256, 0, stream>>>(fb, fd, pbuf, pab, stats,
                                                    scals[prev], U, scals[cur],
                                                    it > 0 ? 1 : 0);
    gru_kernel<<<dim3(BB, 4), 768, 0, stream>>>(U, scals[cur], Wvm, s0v, sin_,
                                                pWih, pWhh, gbih, gbhh, mlng, mlnb,
                                                pW1, b1, pW2, b2, souts[it]);
    sin_ = souts[it];
  }
}

// Round 10
// 536.691 us; speedup vs baseline: 1.4435x; 1.1273x over previous
//
#include <hip/hip_runtime.h>

typedef unsigned short u16;
typedef unsigned int u32;

#define BB 64
#define FF 4096
#define DD 192
#define HH 768

typedef __attribute__((ext_vector_type(8))) __bf16 bf16x8;
typedef __attribute__((ext_vector_type(4))) float f32x4;
typedef __attribute__((ext_vector_type(2))) u32 u32x2;

__device__ __forceinline__ float bf2f(u32 u) {
  union { u32 i; float f; } x; x.i = u << 16; return x.f;
}
__device__ __forceinline__ u16 f2bf(float f) {
  __bf16 h = (__bf16)f;
  return __builtin_bit_cast(u16, h);
}
__device__ __forceinline__ u32 pk2bf(float a, float b) {
  return (u32)f2bf(a) | ((u32)f2bf(b) << 16);
}
__device__ __forceinline__ float sigm(float x) { return 1.f / (1.f + __expf(-x)); }

// ---------------------------------------------------------------------------
// Prep: Wvm[e][d] = g[e]*Wv[e][d] (f32), s0v[d] = b@Wv, s0k[d] = b@Wk.
// ---------------------------------------------------------------------------
__global__ void prep_vw(const float* __restrict__ Wk, const float* __restrict__ Wv,
                        const float* __restrict__ g, const float* __restrict__ bb,
                        float* __restrict__ Wvm, float* __restrict__ s0v,
                        float* __restrict__ s0k) {
  int d = threadIdx.x;  // 0..191
  float av = 0.f, ak = 0.f;
  for (int e = 0; e < DD; ++e) {
    float wv = Wv[e * DD + d];
    Wvm[e * DD + d] = g[e] * wv;
    av += bb[e] * wv;
    ak += bb[e] * Wk[e * DD + d];
  }
  s0v[d] = av; s0k[d] = ak;
}

// Pack GRU/MLP weights to bf16 e-pairs: dst[((g*E2+e/2)*N + n)*2 + (e&1)].
__global__ void prep_packw(const float* __restrict__ Wih, const float* __restrict__ Whh,
                           const float* __restrict__ W1, const float* __restrict__ W2,
                           u16* __restrict__ pWih, u16* __restrict__ pWhh,
                           u16* __restrict__ pW1, u16* __restrict__ pW2) {
  int which = blockIdx.y;
  int total, N, E;
  const float* src; u16* dst; int srcEmajor;
  if (which < 2) { total = 3 * 576 * 192; N = 576; E = 192; srcEmajor = 0;
                   src = which ? Whh : Wih; dst = which ? pWhh : pWih; }
  else if (which == 2) { total = 3 * 192 * 768; N = 768; E = 192; srcEmajor = 1;
                         src = W1; dst = pW1; }
  else { total = 3 * 768 * 192; N = 192; E = 768; srcEmajor = 1; src = W2; dst = pW2; }
  for (int idx = blockIdx.x * 256 + threadIdx.x; idx < total; idx += gridDim.x * 256) {
    int g = idx / (N * E), rem = idx % (N * E);
    int n, e;
    if (srcEmajor) { e = rem / N; n = rem % N; }    // src[g][e][n]
    else { n = rem / E; e = rem % E; }              // src[g][n][e]
    dst[((g * (E / 2) + (e >> 1)) * N + n) * 2 + (e & 1)] = f2bf(src[idx]);
  }
}

// ---------------------------------------------------------------------------
// fconv: feat f32 -> bf16 fb in PV/QK-shared subtiled layout + LN stats.
// fb per 128-token chunk: u16 addr = (nt*32 + T4)*64 + (t&3)*16 + (d&15),
// nt = d>>4, T4 = t>>2.  Block = 64 tokens (half chunk), 256 thr.
// ---------------------------------------------------------------------------
__global__ __launch_bounds__(256) void fconv(const float* __restrict__ feat,
                                             u16* __restrict__ fb,
                                             float2* __restrict__ stats) {
  __shared__ __align__(16) u16 flds[64 * 200];   // token-major, stride 200 (pad)
  int tid = threadIdx.x;
  int blk = blockIdx.x;
  int r = tid >> 2, p = tid & 3;
  long t = (long)blk * 64 + r;
  const float4* src = (const float4*)(feat + t * DD) + p * 12;
  float s = 0.f, s2 = 0.f;
  #pragma unroll
  for (int i = 0; i < 6; ++i) {
    float4 a = src[i * 2], b = src[i * 2 + 1];
    s += a.x + a.y + a.z + a.w + b.x + b.y + b.z + b.w;
    s2 += a.x * a.x + a.y * a.y + a.z * a.z + a.w * a.w +
          b.x * b.x + b.y * b.y + b.z * b.z + b.w * b.w;
    uint4 v;
    v.x = pk2bf(a.x, a.y); v.y = pk2bf(a.z, a.w);
    v.z = pk2bf(b.x, b.y); v.w = pk2bf(b.z, b.w);
    *(uint4*)((char*)flds + r * 400 + p * 96 + i * 16) = v;
  }
  s += __shfl_xor(s, 1); s2 += __shfl_xor(s2, 1);
  s += __shfl_xor(s, 2); s2 += __shfl_xor(s2, 2);
  if (p == 0) {
    float mu = s * (1.f / 192.f);
    float rstd = rsqrtf(s2 * (1.f / 192.f) - mu * mu + 1e-5f);
    stats[t] = make_float2(rstd, mu);
  }
  __syncthreads();
  // write-out: 1536 granules (16B each) in chunk-slot order
  u16* fbc = fb + (size_t)(blk >> 1) * 24576;
  int half = blk & 1;                    // which 64-token half of the chunk
  #pragma unroll
  for (int i = 0; i < 6; ++i) {
    int q = tid + i * 256;               // 0..1535 local granule
    int nt = q / 128, within = q % 128;
    int T4loc = within >> 3, sub = within & 7;
    int tloc = T4loc * 4 + (sub >> 1);   // 0..63
    int d0 = nt * 16 + (sub & 1) * 8;
    uint4 v = *(uint4*)(flds + tloc * 200 + d0);
    int slot = nt * 256 + (half * 16 + T4loc) * 8 + sub;
    *(uint4*)(fbc + slot * 8) = v;
  }
}

// ---------------------------------------------------------------------------
// q projection + p = g ⊙ (Wk @ q), alpha = sum(bf16(p)), beta = s0k·q.
// One wave per (b,slot).  Also zeroes scal_cur and pbuf rows 8..15.
// ---------------------------------------------------------------------------
__global__ __launch_bounds__(64) void qproj_kernel(
    const float* __restrict__ slots, const float* __restrict__ Wq,
    const float* __restrict__ lsg, const float* __restrict__ lsb,
    const float* __restrict__ Wk, const float* __restrict__ lfg,
    const float* __restrict__ s0k,
    u16* __restrict__ pbuf, float* __restrict__ pab,
    float* __restrict__ scal_cur) {
  __shared__ float ln[192];
  int bk = blockIdx.x;
  int b = bk >> 3, sl = bk & 7;
  int lane = threadIdx.x;
  {
    int gtid = bk * 64 + lane;
    if (gtid < 512) ((float4*)scal_cur)[gtid] = (float4){0.f, 0.f, 0.f, 0.f};
  }
  const float* x = slots + bk * DD;
  float v0 = x[lane], v1 = x[lane + 64], v2 = x[lane + 128];
  float s = v0 + v1 + v2, s2 = v0 * v0 + v1 * v1 + v2 * v2;
  #pragma unroll
  for (int m = 1; m < 64; m <<= 1) { s += __shfl_xor(s, m); s2 += __shfl_xor(s2, m); }
  float mu = s * (1.f / 192.f);
  float rstd = rsqrtf(s2 * (1.f / 192.f) - mu * mu + 1e-5f);
  ln[lane]       = (v0 - mu) * rstd * lsg[lane]       + lsb[lane];
  ln[lane + 64]  = (v1 - mu) * rstd * lsg[lane + 64]  + lsb[lane + 64];
  ln[lane + 128] = (v2 - mu) * rstd * lsg[lane + 128] + lsb[lane + 128];
  __syncthreads();
  float a0 = 0.f, a1 = 0.f, a2 = 0.f;
  for (int e = 0; e < DD; ++e) {
    float le = ln[e];
    a0 += le * Wq[e * DD + lane];
    a1 += le * Wq[e * DD + lane + 64];
    a2 += le * Wq[e * DD + lane + 128];
  }
  __syncthreads();
  const float scale = 0.07216878364870323f;  // 192^-0.5
  ln[lane] = a0 * scale; ln[lane + 64] = a1 * scale; ln[lane + 128] = a2 * scale;
  __syncthreads();
  float al = 0.f, be = 0.f;
  u16 pb[3];
  #pragma unroll
  for (int k3 = 0; k3 < 3; ++k3) {
    int d = lane + k3 * 64;
    const float* wr = Wk + (size_t)d * DD;
    float pd = 0.f;
    for (int e = 0; e < DD; ++e) pd += wr[e] * ln[e];
    pd *= lfg[d];
    u16 h = f2bf(pd);
    pb[k3] = h;
    al += bf2f(h);
    be += s0k[d] * ln[d];
  }
  #pragma unroll
  for (int m = 1; m < 64; m <<= 1) { al += __shfl_xor(al, m); be += __shfl_xor(be, m); }
  #pragma unroll
  for (int k3 = 0; k3 < 3; ++k3)
    pbuf[(b * 16 + sl) * DD + lane + k3 * 64] = pb[k3];
  if (lane < 24) *(uint4*)(pbuf + (b * 16 + 8 + sl) * DD + lane * 8) = (uint4){0, 0, 0, 0};
  if (lane == 0) { pab[bk * 2] = al; pab[bk * 2 + 1] = be; }
}

// ---------------------------------------------------------------------------
// Fused attention + update, single-layout f: stage 128-token fb chunk to LDS
// (global_load_lds, linear), QK reads rows, PV reads via ds_read_b64_tr_b16.
// attn written k-permuted to match tr-read token order.  grid (B, 32).
// ---------------------------------------------------------------------------
__global__ __launch_bounds__(256) void attnpv_kernel(
    const u16* __restrict__ fb, const u16* __restrict__ pbuf,
    const float* __restrict__ pab, const float2* __restrict__ stats,
    const float* __restrict__ scal_prev,
    float* __restrict__ U_part, float* __restrict__ scal_cur, int have_bias) {
  __shared__ __align__(16) u16 ftile[24576];        // 48 KB, fb chunk layout
  __shared__ __align__(16) u16 plds[16 * 192];
  __shared__ __align__(16) u16 attn_lds[16 * 128];  // [slot][k-perm], XOR-swizzled
  int b = blockIdx.x, cy = blockIdx.y;
  int tid = threadIdx.x;
  int w = tid >> 6, lane = tid & 63;
  int l15 = lane & 15, l4 = lane >> 4;
  // stage p (swizzled) + zero attn rows 8..15
  #pragma unroll
  for (int i = 0; i < 2; ++i) {
    int g = tid + i * 256;
    if (g < 384) {
      int s = g / 24, u = g % 24;
      uint4 v = *(const uint4*)(pbuf + ((b * 16 + s) * DD + u * 8));
      *(uint4*)((char*)plds + s * 384 + ((u ^ (s & 7)) << 4)) = v;
    }
  }
  if (tid < 128) *(uint4*)((char*)attn_lds + 2048 + tid * 16) = (uint4){0, 0, 0, 0};
  // bulk stage ftile: 3072 granules, 12 wave-instructions per wave
  {
    const u16* fbc = fb + (size_t)(b * 32 + cy) * 24576;
    #pragma unroll
    for (int j = 0; j < 12; ++j) {
      int g = w * 768 + j * 64;                      // wave-uniform granule base
      __builtin_amdgcn_global_load_lds((const u32*)(fbc + (size_t)(g + lane) * 8),
                                       (u32*)&ftile[g * 8], 16, 0, 0);
    }
  }
  __syncthreads();
  bf16x8 qfr[6];
  #pragma unroll
  for (int kk = 0; kk < 6; ++kk) {
    int u = kk * 4 + l4;
    qfr[kk] = *(bf16x8*)((char*)plds + l15 * 384 + ((u ^ (l15 & 7)) << 4));
  }
  float ax[4], ay[4], c0[4], av[4], bv[4];
  #pragma unroll
  for (int j = 0; j < 4; ++j) {
    int s = l4 * 4 + j;
    if (s < 8) {
      av[j] = pab[(b * 8 + s) * 2];
      bv[j] = pab[(b * 8 + s) * 2 + 1];
      if (have_bias) {
        float inv = 1.f / (scal_prev[(b * 8 + s) * 4] + 1e-8f);
        float cx = scal_prev[(b * 8 + s) * 4 + 1] * inv;
        float cy2 = scal_prev[(b * 8 + s) * 4 + 2] * inv;
        ax[j] = 16.f * cx; ay[j] = 16.f * cy2; c0[j] = -8.f * (cx * cx + cy2 * cy2);
      } else { ax[j] = 0.f; ay[j] = 0.f; c0[j] = 0.f; }
    } else { av[j] = 0.f; bv[j] = 0.f; ax[j] = 0.f; ay[j] = 0.f; c0[j] = 0.f; }
  }
  float pa[4], px[4], py[4], pg[4];
  #pragma unroll
  for (int j = 0; j < 4; ++j) { pa[j] = 0.f; px[j] = 0.f; py[j] = 0.f; pg[j] = 0.f; }
  #pragma unroll
  for (int tt = 0; tt < 2; ++tt) {
    int tile = w + tt * 4;
    int t128 = tile * 16 + l15;
    int trow = (t128 >> 2) * 64 + (t128 & 3) * 16;   // u16 units
    f32x4 acc = (f32x4){0.f, 0.f, 0.f, 0.f};
    #pragma unroll
    for (int kk = 0; kk < 6; ++kk) {
      int u = kk * 4 + l4;
      bf16x8 bfr = *(bf16x8*)(ftile + (u >> 1) * 2048 + trow + (u & 1) * 8);
      acc = __builtin_amdgcn_mfma_f32_16x16x32_bf16(qfr[kk], bfr, acc, 0, 0, 0);
    }
    int t = cy * 128 + t128;
    float2 st = stats[((long)b << 12) + t];
    float rstd = st.x, muv = st.y;
    float x = -1.f + (float)(t & 63) * (2.f / 63.f);
    float y = -1.f + (float)(t >> 6) * (2.f / 63.f);
    float m8r2 = -8.f * (x * x + y * y);
    float d4[4];
    #pragma unroll
    for (int j = 0; j < 4; ++j)
      d4[j] = rstd * acc[j] - rstd * muv * av[j] + bv[j] +
              (have_bias ? (ax[j] * x + ay[j] * y + c0[j] + m8r2) : 0.f);
    float o4[4];
    #pragma unroll
    for (int j = 0; j < 4; ++j) o4[j] = __shfl_xor(d4[j], 16);
    float mx = fmaxf(fmaxf(fmaxf(d4[0], d4[1]), fmaxf(d4[2], d4[3])),
                     fmaxf(fmaxf(o4[0], o4[1]), fmaxf(o4[2], o4[3])));
    float e4[4];
    float sum = 0.f;
    #pragma unroll
    for (int j = 0; j < 4; ++j) { e4[j] = __expf(d4[j] - mx); sum += e4[j]; }
    #pragma unroll
    for (int j = 0; j < 4; ++j) sum += __expf(o4[j] - mx);
    float inv = 1.f / sum;
    if (l4 < 2) {
      int t5 = t128 & 31;
      int kidx = ((t5 >> 2) & 3) * 8 + ((t5 >> 4) & 1) * 4 + (t5 & 3);
      int k128 = (t128 & ~31) | kidx;
      #pragma unroll
      for (int j = 0; j < 4; ++j) {
        float a = e4[j] * inv;
        u16 wr = f2bf(a * rstd);
        int s = l4 * 4 + j;
        *(u16*)((char*)attn_lds + ((s * 256 + k128 * 2) ^ ((s & 7) << 4))) = wr;
        pa[j] += a; px[j] += a * x; py[j] += a * y;
        pg[j] += bf2f(wr) * muv;
      }
    }
  }
  #pragma unroll
  for (int m = 1; m < 16; m <<= 1) {
    #pragma unroll
    for (int j = 0; j < 4; ++j) {
      pa[j] += __shfl_xor(pa[j], m);
      px[j] += __shfl_xor(px[j], m);
      py[j] += __shfl_xor(py[j], m);
      pg[j] += __shfl_xor(pg[j], m);
    }
  }
  if (l15 == 0 && l4 < 2) {
    #pragma unroll
    for (int j = 0; j < 4; ++j) {
      int s = l4 * 4 + j;
      atomicAdd(&scal_cur[(b * 8 + s) * 4], pa[j]);
      atomicAdd(&scal_cur[(b * 8 + s) * 4 + 1], px[j]);
      atomicAdd(&scal_cur[(b * 8 + s) * 4 + 2], py[j]);
      atomicAdd(&scal_cur[(b * 8 + s) * 4 + 3], pg[j]);
    }
  }
  __syncthreads();
  // ---- PV: A = attn (k-perm layout), B = f via hardware transpose reads ----
  u32 ldsbase = (u32)(size_t)&ftile[0];
  f32x4 pacc[3];
  #pragma unroll
  for (int ni = 0; ni < 3; ++ni) pacc[ni] = (f32x4){0.f, 0.f, 0.f, 0.f};
  #pragma unroll
  for (int ni = 0; ni < 3; ++ni) {
    int nt = w * 3 + ni;
    #pragma unroll
    for (int g = 0; g < 4; ++g) {
      u32 a = ldsbase + nt * 4096 + g * 1024 + lane * 8;
      u32x2 lo, hi;
      asm volatile("ds_read_b64_tr_b16 %0, %2\n\t"
                   "ds_read_b64_tr_b16 %1, %2 offset:512"
                   : "=&v"(lo), "=&v"(hi) : "v"(a));
      asm volatile("s_waitcnt lgkmcnt(0)" ::: "memory");
      __builtin_amdgcn_sched_barrier(0);
      union { u32 u[4]; bf16x8 v; } bb_;
      bb_.u[0] = lo.x; bb_.u[1] = lo.y; bb_.u[2] = hi.x; bb_.u[3] = hi.y;
      bf16x8 afr = *(bf16x8*)((char*)attn_lds +
                              ((l15 * 256 + g * 64 + l4 * 16) ^ ((l15 & 7) << 4)));
      pacc[ni] = __builtin_amdgcn_mfma_f32_16x16x32_bf16(afr, bb_.v, pacc[ni], 0, 0, 0);
    }
  }
  if (l4 < 2) {
    float* up = U_part + (size_t)(b * 32 + cy) * 1536;
    #pragma unroll
    for (int ni = 0; ni < 3; ++ni) {
      int nt = w * 3 + ni;
      #pragma unroll
      for (int j = 0; j < 4; ++j)
        up[(l4 * 4 + j) * 192 + nt * 16 + l15] = pacc[ni][j];
    }
  }
}

// ---------------------------------------------------------------------------
// GRU + LN + MLP.  768 threads; first phase sums U_part partials, then
// upd = ((U - gamma) @ Wvm + asum*s0v) / (asum+eps).
// ---------------------------------------------------------------------------
template <int M>
__device__ void gru_body(int b0, int g, int srow,
                         float* u_l, float* h_l, float* gi_l, float* gh_l,
                         float* hn_l, float* ln_l, float* x1_l, float* out_l, float* st,
                         const float* __restrict__ U_part, const float* __restrict__ scal,
                         const float* __restrict__ Wvm, const float* __restrict__ s0v,
                         const float* __restrict__ sin_,
                         const u16* __restrict__ pWih, const u16* __restrict__ pWhh,
                         const float* __restrict__ bih, const float* __restrict__ bhh,
                         const float* __restrict__ mlng, const float* __restrict__ mlnb,
                         const u16* __restrict__ pW1, const float* __restrict__ b1,
                         const u16* __restrict__ pW2, const float* __restrict__ b2,
                         float* __restrict__ sout) {
  int tid = threadIdx.x;
  for (int idx = tid; idx < M * 192; idx += 768) {
    int row = idx / 192, d = idx % 192;
    int gr = b0 * 8 + srow + row;
    float acc = 0.f;
    const float* upb = U_part + (size_t)b0 * 32 * 1536 + (srow + row) * 192 + d;
    #pragma unroll 4
    for (int c = 0; c < 32; ++c) acc += upb[c * 1536];
    hn_l[row * 192 + d] = acc;
    h_l[row * 192 + d] = sin_[gr * DD + d];
  }
  __syncthreads();
  if (tid < M * 192) {
    int row = tid / 192, d = tid % 192;
    int gr = b0 * 8 + srow + row;
    float asum = scal[gr * 4], gam = scal[gr * 4 + 3];
    float inv = 1.f / (asum + 1e-8f);
    float acc = asum * s0v[d];
    const float* ur = hn_l + row * 192;
    #pragma unroll 4
    for (int e = 0; e < DD; ++e) acc += (ur[e] - gam) * Wvm[e * DD + d];
    u_l[row * 192 + d] = acc * inv;
  }
  __syncthreads();
  if (tid < 576) {
    int c = tid;
    const u16* wih = pWih + (size_t)g * 96 * 1152 + c * 2;
    const u16* whh = pWhh + (size_t)g * 96 * 1152 + c * 2;
    float ai[M], ah[M];
    #pragma unroll
    for (int r = 0; r < M; ++r) { ai[r] = 0.f; ah[r] = 0.f; }
    #pragma unroll 4
    for (int e2 = 0; e2 < 96; ++e2) {
      u32 wi = *(const u32*)(wih + e2 * 1152);
      u32 wh = *(const u32*)(whh + e2 * 1152);
      float wi0 = bf2f(wi & 0xffffu), wi1 = bf2f(wi >> 16);
      float wh0 = bf2f(wh & 0xffffu), wh1 = bf2f(wh >> 16);
      #pragma unroll
      for (int r = 0; r < M; ++r) {
        ai[r] += wi0 * u_l[r * 192 + e2 * 2] + wi1 * u_l[r * 192 + e2 * 2 + 1];
        ah[r] += wh0 * h_l[r * 192 + e2 * 2] + wh1 * h_l[r * 192 + e2 * 2 + 1];
      }
    }
    #pragma unroll
    for (int r = 0; r < M; ++r) { gi_l[r * 576 + c] = ai[r]; gh_l[r * 576 + c] = ah[r]; }
  }
  __syncthreads();
  if (tid < M * 192) {
    int row = tid / 192, uu = tid % 192;
    const float* bihg = bih + g * 576;
    const float* bhhg = bhh + g * 576;
    float r_ = sigm(gi_l[row * 576 + uu] + bihg[uu] + gh_l[row * 576 + uu] + bhhg[uu]);
    float z_ = sigm(gi_l[row * 576 + 192 + uu] + bihg[192 + uu] +
                    gh_l[row * 576 + 192 + uu] + bhhg[192 + uu]);
    float nn = gi_l[row * 576 + 384 + uu] + bihg[384 + uu] +
               r_ * (gh_l[row * 576 + 384 + uu] + bhhg[384 + uu]);
    float t = 1.f - 2.f / (__expf(2.f * nn) + 1.f);
    hn_l[row * 192 + uu] = (1.f - z_) * t + z_ * h_l[row * 192 + uu];
  }
  __syncthreads();
  {
    int wv = tid >> 6, lane = tid & 63;
    if (wv < M) {
      float v0 = hn_l[wv * 192 + lane], v1 = hn_l[wv * 192 + lane + 64],
            v2 = hn_l[wv * 192 + lane + 128];
      float s = v0 + v1 + v2, sq = v0 * v0 + v1 * v1 + v2 * v2;
      #pragma unroll
      for (int m = 1; m < 64; m <<= 1) { s += __shfl_xor(s, m); sq += __shfl_xor(sq, m); }
      if (lane == 0) {
        float mu = s * (1.f / 192.f);
        st[wv * 2] = mu;
        st[wv * 2 + 1] = rsqrtf(sq * (1.f / 192.f) - mu * mu + 1e-5f);
      }
    }
  }
  __syncthreads();
  if (tid < M * 192) {
    int row = tid / 192, uu = tid % 192;
    ln_l[row * 192 + uu] = (hn_l[row * 192 + uu] - st[row * 2]) * st[row * 2 + 1] *
                               mlng[g * DD + uu] + mlnb[g * DD + uu];
  }
  __syncthreads();
  {
    int c = tid;
    const u16* w1 = pW1 + (size_t)g * 96 * 1536 + c * 2;
    float a[M];
    #pragma unroll
    for (int r = 0; r < M; ++r) a[r] = 0.f;
    #pragma unroll 4
    for (int e2 = 0; e2 < 96; ++e2) {
      u32 wp = *(const u32*)(w1 + e2 * 1536);
      float w0 = bf2f(wp & 0xffffu), w1f = bf2f(wp >> 16);
      #pragma unroll
      for (int r = 0; r < M; ++r)
        a[r] += w0 * ln_l[r * 192 + e2 * 2] + w1f * ln_l[r * 192 + e2 * 2 + 1];
    }
    float bc = b1[g * HH + c];
    #pragma unroll
    for (int r = 0; r < M; ++r) x1_l[r * 768 + c] = fmaxf(a[r] + bc, 0.f);
  }
  if (tid < M * 192) {
    int row = tid / 192, uu = tid % 192;
    out_l[row * 192 + uu] = hn_l[row * 192 + uu] + b2[g * DD + uu];
  }
  __syncthreads();
  {
    int c = tid % 192, ks = tid / 192;
    const u16* w2 = pW2 + (size_t)g * 384 * 384 + c * 2;
    float a[M];
    #pragma unroll
    for (int r = 0; r < M; ++r) a[r] = 0.f;
    #pragma unroll 4
    for (int e2 = ks * 96; e2 < ks * 96 + 96; ++e2) {
      u32 wp = *(const u32*)(w2 + e2 * 384);
      float w0 = bf2f(wp & 0xffffu), w1f = bf2f(wp >> 16);
      #pragma unroll
      for (int r = 0; r < M; ++r)
        a[r] += w0 * x1_l[r * 768 + e2 * 2] + w1f * x1_l[r * 768 + e2 * 2 + 1];
    }
    #pragma unroll
    for (int r = 0; r < M; ++r) atomicAdd(&out_l[r * 192 + c], a[r]);
  }
  __syncthreads();
  if (tid < M * 192) {
    int row = tid / 192, d = tid % 192;
    sout[(b0 * 8 + srow + row) * DD + d] = out_l[row * 192 + d];
  }
}

__global__ __launch_bounds__(768) void gru_kernel(
    const float* __restrict__ U_part, const float* __restrict__ scal,
    const float* __restrict__ Wvm, const float* __restrict__ s0v,
    const float* __restrict__ sin_,
    const u16* __restrict__ pWih, const u16* __restrict__ pWhh,
    const float* __restrict__ bih, const float* __restrict__ bhh,
    const float* __restrict__ mlng, const float* __restrict__ mlnb,
    const u16* __restrict__ pW1, const float* __restrict__ b1,
    const u16* __restrict__ pW2, const float* __restrict__ b2,
    float* __restrict__ sout) {
  __shared__ float u_l[3 * 192], h_l[3 * 192], gi_l[3 * 576], gh_l[3 * 576];
  __shared__ float hn_l[3 * 192], ln_l[3 * 192], x1_l[3 * 768], out_l[3 * 192], st[8];
  int b = blockIdx.x, y = blockIdx.y;
  if (y == 0)
    gru_body<1>(b, 0, 0, u_l, h_l, gi_l, gh_l, hn_l, ln_l, x1_l, out_l, st,
                U_part, scal, Wvm, s0v, sin_, pWih, pWhh, bih, bhh, mlng, mlnb,
                pW1, b1, pW2, b2, sout);
  else if (y == 1)
    gru_body<1>(b, 2, 7, u_l, h_l, gi_l, gh_l, hn_l, ln_l, x1_l, out_l, st,
                U_part, scal, Wvm, s0v, sin_, pWih, pWhh, bih, bhh, mlng, mlnb,
                pW1, b1, pW2, b2, sout);
  else if (y == 2)
    gru_body<3>(b, 1, 1, u_l, h_l, gi_l, gh_l, hn_l, ln_l, x1_l, out_l, st,
                U_part, scal, Wvm, s0v, sin_, pWih, pWhh, bih, bhh, mlng, mlnb,
                pW1, b1, pW2, b2, sout);
  else
    gru_body<3>(b, 1, 4, u_l, h_l, gi_l, gh_l, hn_l, ln_l, x1_l, out_l, st,
                U_part, scal, Wvm, s0v, sin_, pWih, pWhh, bih, bhh, mlng, mlnb,
                pW1, b1, pW2, b2, sout);
}

// ---------------------------------------------------------------------------
extern "C" void kernel_launch(void* const* d_in, const int* in_sizes, int n_in,
                              void* d_out, int out_size, void* d_ws, size_t ws_size,
                              hipStream_t stream) {
  const float* feat = (const float*)d_in[0];
  const float* slots = (const float*)d_in[1];
  const float* Wk = (const float*)d_in[2];
  const float* Wv = (const float*)d_in[3];
  const float* Wq = (const float*)d_in[4];
  const float* lfg = (const float*)d_in[5];
  const float* lfb = (const float*)d_in[6];
  const float* lsg = (const float*)d_in[7];
  const float* lsb = (const float*)d_in[8];
  const float* gWih = (const float*)d_in[9];
  const float* gWhh = (const float*)d_in[10];
  const float* gbih = (const float*)d_in[11];
  const float* gbhh = (const float*)d_in[12];
  const float* mlng = (const float*)d_in[13];
  const float* mlnb = (const float*)d_in[14];
  const float* W1 = (const float*)d_in[15];
  const float* b1 = (const float*)d_in[16];
  const float* W2 = (const float*)d_in[17];
  const float* b2 = (const float*)d_in[18];
  float* out = (float*)d_out;

  char* ws = (char*)d_ws;
  size_t off = 0;
  auto alloc = [&](size_t bytes) {
    void* p = ws + off;
    off += (bytes + 255) & ~(size_t)255;
    return p;
  };
  u16* fb       = (u16*)alloc((size_t)BB * FF * DD * 2);
  float2* stats = (float2*)alloc((size_t)BB * FF * 8);
  u16* pbuf     = (u16*)alloc((size_t)BB * 16 * DD * 2);
  float* pab    = (float*)alloc((size_t)BB * 8 * 2 * 4);
  float* U_part = (float*)alloc((size_t)BB * 32 * 8 * DD * 4);
  float* slA    = (float*)alloc((size_t)BB * 8 * DD * 4);
  float* slB    = (float*)alloc((size_t)BB * 8 * DD * 4);
  float* scal0  = (float*)alloc(BB * 8 * 4 * 4);
  float* scal1  = (float*)alloc(BB * 8 * 4 * 4);
  float* Wvm    = (float*)alloc((size_t)DD * DD * 4);
  float* s0v    = (float*)alloc(DD * 4);
  float* s0k    = (float*)alloc(DD * 4);
  u16* pWih     = (u16*)alloc((size_t)3 * 576 * DD * 2);
  u16* pWhh     = (u16*)alloc((size_t)3 * 576 * DD * 2);
  u16* pW1      = (u16*)alloc((size_t)3 * DD * HH * 2);
  u16* pW2      = (u16*)alloc((size_t)3 * HH * DD * 2);

  prep_vw<<<1, 192, 0, stream>>>(Wk, Wv, lfg, lfb, Wvm, s0v, s0k);
  prep_packw<<<dim3(432, 4), 256, 0, stream>>>(gWih, gWhh, W1, W2, pWih, pWhh, pW1, pW2);
  fconv<<<BB * FF / 64, 256, 0, stream>>>(feat, fb, stats);

  const float* sin_ = slots;
  float* souts[3] = {slA, slB, out};
  float* scals[2] = {scal0, scal1};
  for (int it = 0; it < 3; ++it) {
    int cur = it & 1, prev = cur ^ 1;
    qproj_kernel<<<BB * 8, 64, 0, stream>>>(sin_, Wq, lsg, lsb, Wk, lfg, s0k,
                                            pbuf, pab, scals[cur]);
    attnpv_kernel<<<dim3(BB, 32), 256, 0, stream>>>(fb, pbuf, pab, stats,
                                                    scals[prev], U_part, scals[cur],
                                                    it > 0 ? 1 : 0);
    gru_kernel<<<dim3(BB, 4), 768, 0, stream>>>(U_part, scals[cur], Wvm, s0v, sin_,
                                                pWih, pWhh, gbih, gbhh, mlng, mlnb,
                                                pW1, b1, pW2, b2, souts[it]);
    sin_ = souts[it];
  }
}

// Round 11
// 513.427 us; speedup vs baseline: 1.5089x; 1.0453x over previous
//
#include <hip/hip_runtime.h>

typedef unsigned short u16;
typedef unsigned int u32;

#define BB 64
#define FF 4096
#define DD 192
#define HH 768

typedef __attribute__((ext_vector_type(8))) __bf16 bf16x8;
typedef __attribute__((ext_vector_type(4))) float f32x4;

__device__ __forceinline__ float bf2f(u32 u) {
  union { u32 i; float f; } x; x.i = u << 16; return x.f;
}
__device__ __forceinline__ u16 f2bf(float f) {
  __bf16 h = (__bf16)f;
  return __builtin_bit_cast(u16, h);
}
__device__ __forceinline__ u32 pk2bf(float a, float b) {
  return (u32)f2bf(a) | ((u32)f2bf(b) << 16);
}
__device__ __forceinline__ float sigm(float x) { return 1.f / (1.f + __expf(-x)); }

// ---------------------------------------------------------------------------
// Prep: Wvm[e][d] = g[e]*Wv[e][d] (f32), s0v[d] = b@Wv, s0k[d] = b@Wk.
// ---------------------------------------------------------------------------
__global__ void prep_vw(const float* __restrict__ Wk, const float* __restrict__ Wv,
                        const float* __restrict__ g, const float* __restrict__ bb,
                        float* __restrict__ Wvm, float* __restrict__ s0v,
                        float* __restrict__ s0k) {
  int d = threadIdx.x;  // 0..191
  float av = 0.f, ak = 0.f;
  for (int e = 0; e < DD; ++e) {
    float wv = Wv[e * DD + d];
    Wvm[e * DD + d] = g[e] * wv;
    av += bb[e] * wv;
    ak += bb[e] * Wk[e * DD + d];
  }
  s0v[d] = av; s0k[d] = ak;
}

// Pack GRU/MLP weights to bf16 e-pairs: dst[((g*E2+e/2)*N + n)*2 + (e&1)].
__global__ void prep_packw(const float* __restrict__ Wih, const float* __restrict__ Whh,
                           const float* __restrict__ W1, const float* __restrict__ W2,
                           u16* __restrict__ pWih, u16* __restrict__ pWhh,
                           u16* __restrict__ pW1, u16* __restrict__ pW2) {
  int which = blockIdx.y;
  int total, N, E;
  const float* src; u16* dst; int srcEmajor;
  if (which < 2) { total = 3 * 576 * 192; N = 576; E = 192; srcEmajor = 0;
                   src = which ? Whh : Wih; dst = which ? pWhh : pWih; }
  else if (which == 2) { total = 3 * 192 * 768; N = 768; E = 192; srcEmajor = 1;
                         src = W1; dst = pW1; }
  else { total = 3 * 768 * 192; N = 192; E = 768; srcEmajor = 1; src = W2; dst = pW2; }
  for (int idx = blockIdx.x * 256 + threadIdx.x; idx < total; idx += gridDim.x * 256) {
    int g = idx / (N * E), rem = idx % (N * E);
    int n, e;
    if (srcEmajor) { e = rem / N; n = rem % N; }    // src[g][e][n]
    else { n = rem / E; e = rem % E; }              // src[g][n][e]
    dst[((g * (E / 2) + (e >> 1)) * N + n) * 2 + (e & 1)] = f2bf(src[idx]);
  }
}

// ---------------------------------------------------------------------------
// fconv: stream feat f32 -> bf16 in two layouts + per-token LN stats.
// fb: QK granules [Tg][u(24)][tau16][8dims].  fd: PV granules
// [((b*128+g32)*12+ntg)*64 + l4f*16 + (d&15)][8toks].  stats[t]={rstd, mu}.
// ---------------------------------------------------------------------------
__global__ __launch_bounds__(256) void fconv(const float* __restrict__ feat,
                                             u16* __restrict__ fb, u16* __restrict__ fd,
                                             float2* __restrict__ stats) {
  __shared__ __align__(16) u16 flds[64 * 192];   // token-major bf16 tile
  int tid = threadIdx.x;
  int blk = blockIdx.x;
  int r = tid >> 2, p = tid & 3;
  long t = (long)blk * 64 + r;
  const float4* src = (const float4*)(feat + t * DD) + p * 12;
  float s = 0.f, s2 = 0.f;
  long Tg = t >> 4; int tau = (int)(t & 15);
  #pragma unroll
  for (int i = 0; i < 6; ++i) {
    float4 a = src[i * 2], b = src[i * 2 + 1];
    s += a.x + a.y + a.z + a.w + b.x + b.y + b.z + b.w;
    s2 += a.x * a.x + a.y * a.y + a.z * a.z + a.w * a.w +
          b.x * b.x + b.y * b.y + b.z * b.z + b.w * b.w;
    uint4 v;
    v.x = pk2bf(a.x, a.y); v.y = pk2bf(a.z, a.w);
    v.z = pk2bf(b.x, b.y); v.w = pk2bf(b.z, b.w);
    int u = p * 6 + i;
    *(uint4*)(fb + ((Tg * 24 + u) * 16 + tau) * 8) = v;
    *(uint4*)((char*)flds + r * 384 + p * 96 + i * 16) = v;
  }
  s += __shfl_xor(s, 1); s2 += __shfl_xor(s2, 1);
  s += __shfl_xor(s, 2); s2 += __shfl_xor(s2, 2);
  if (p == 0) {
    float mu = s * (1.f / 192.f);
    float rstd = rsqrtf(s2 * (1.f / 192.f) - mu * mu + 1e-5f);
    stats[t] = make_float2(rstd, mu);
  }
  __syncthreads();
  // fd pass: granule = (8 tokens, 1 dim).  idx -> (tg8 = token-octet, d).
  int b = blk >> 6;
  #pragma unroll
  for (int i = 0; i < 6; ++i) {
    int idx = tid + i * 256;            // 0..1535
    int tg8 = idx / 192, d = idx % 192;
    u16 h[8];
    #pragma unroll
    for (int j = 0; j < 8; ++j) h[j] = flds[(tg8 * 8 + j) * 192 + d];
    uint4 v;
    v.x = (u32)h[0] | ((u32)h[1] << 16);
    v.y = (u32)h[2] | ((u32)h[3] << 16);
    v.z = (u32)h[4] | ((u32)h[5] << 16);
    v.w = (u32)h[6] | ((u32)h[7] << 16);
    int g32 = (blk & 63) * 2 + (tg8 >> 2);
    int l4f = tg8 & 3;
    *(uint4*)(fd + ((((long)b * 128 + g32) * 12 + (d >> 4)) * 64 + l4f * 16 +
                    (d & 15)) * 8) = v;
  }
}

// ---------------------------------------------------------------------------
// Standalone q projection (iteration 0 only): q = LN(slots)@Wq*scale,
// p = lfg ⊙ (Wk@q), alpha = sum bf16(p), beta = s0k·q.
// Also zeroes scal_cur and pbuf rows 8..15.
// ---------------------------------------------------------------------------
__global__ __launch_bounds__(64) void qproj_kernel(
    const float* __restrict__ slots, const float* __restrict__ Wq,
    const float* __restrict__ lsg, const float* __restrict__ lsb,
    const float* __restrict__ Wk, const float* __restrict__ lfg,
    const float* __restrict__ s0k,
    u16* __restrict__ pbuf, float* __restrict__ pab,
    float* __restrict__ scal_cur) {
  __shared__ float ln[192];
  int bk = blockIdx.x;
  int b = bk >> 3, sl = bk & 7;
  int lane = threadIdx.x;
  {
    int gtid = bk * 64 + lane;
    if (gtid < 512) ((float4*)scal_cur)[gtid] = (float4){0.f, 0.f, 0.f, 0.f};
  }
  const float* x = slots + bk * DD;
  float v0 = x[lane], v1 = x[lane + 64], v2 = x[lane + 128];
  float s = v0 + v1 + v2, s2 = v0 * v0 + v1 * v1 + v2 * v2;
  #pragma unroll
  for (int m = 1; m < 64; m <<= 1) { s += __shfl_xor(s, m); s2 += __shfl_xor(s2, m); }
  float mu = s * (1.f / 192.f);
  float rstd = rsqrtf(s2 * (1.f / 192.f) - mu * mu + 1e-5f);
  ln[lane]       = (v0 - mu) * rstd * lsg[lane]       + lsb[lane];
  ln[lane + 64]  = (v1 - mu) * rstd * lsg[lane + 64]  + lsb[lane + 64];
  ln[lane + 128] = (v2 - mu) * rstd * lsg[lane + 128] + lsb[lane + 128];
  __syncthreads();
  float a0 = 0.f, a1 = 0.f, a2 = 0.f;
  for (int e = 0; e < DD; ++e) {
    float le = ln[e];
    a0 += le * Wq[e * DD + lane];
    a1 += le * Wq[e * DD + lane + 64];
    a2 += le * Wq[e * DD + lane + 128];
  }
  __syncthreads();
  const float scale = 0.07216878364870323f;  // 192^-0.5
  ln[lane] = a0 * scale; ln[lane + 64] = a1 * scale; ln[lane + 128] = a2 * scale;
  __syncthreads();
  float al = 0.f, be = 0.f;
  u16 pb[3];
  #pragma unroll
  for (int k3 = 0; k3 < 3; ++k3) {
    int d = lane + k3 * 64;
    const float* wr = Wk + (size_t)d * DD;
    float pd = 0.f;
    for (int e = 0; e < DD; ++e) pd += wr[e] * ln[e];
    pd *= lfg[d];
    u16 h = f2bf(pd);
    pb[k3] = h;
    al += bf2f(h);
    be += s0k[d] * ln[d];
  }
  #pragma unroll
  for (int m = 1; m < 64; m <<= 1) { al += __shfl_xor(al, m); be += __shfl_xor(be, m); }
  #pragma unroll
  for (int k3 = 0; k3 < 3; ++k3)
    pbuf[(b * 16 + sl) * DD + lane + k3 * 64] = pb[k3];
  if (lane < 24) *(uint4*)(pbuf + (b * 16 + 8 + sl) * DD + lane * 8) = (uint4){0, 0, 0, 0};
  if (lane == 0) { pab[bk * 2] = al; pab[bk * 2 + 1] = be; }
}

// ---------------------------------------------------------------------------
// Fused attention + update on raw features:
// dots = rstd*(f.p) - rstd*mu*alpha + beta (+bias) -> softmax over 8 ->
// w' = attn*rstd to LDS -> PV MFMA -> U_part stores (no atomics).
// grid (B, 16): 256 tokens per block.
// ---------------------------------------------------------------------------
__global__ __launch_bounds__(256) void attnpv_kernel(
    const u16* __restrict__ fb, const u16* __restrict__ fd,
    const u16* __restrict__ pbuf, const float* __restrict__ pab,
    const float2* __restrict__ stats,
    const float* __restrict__ scal_prev,
    float* __restrict__ U_part, float* __restrict__ scal_cur, int have_bias) {
  __shared__ __align__(16) u16 plds[16 * 192];
  __shared__ __align__(16) u16 attn_lds[16 * 256];   // [slot][token], XOR-swizzled
  int b = blockIdx.x, cy = blockIdx.y;
  int chunk = cy * 256;
  int tid = threadIdx.x;
  #pragma unroll
  for (int i = 0; i < 2; ++i) {
    int g = tid + i * 256;
    if (g < 384) {
      int s = g / 24, u = g % 24;
      uint4 v = *(const uint4*)(pbuf + ((b * 16 + s) * DD + u * 8));
      *(uint4*)((char*)plds + s * 384 + ((u ^ (s & 7)) << 4)) = v;
    }
  }
  *(uint4*)((char*)attn_lds + 4096 + tid * 16) = (uint4){0, 0, 0, 0};
  __syncthreads();
  int w = tid >> 6, lane = tid & 63;
  int l15 = lane & 15, l4 = lane >> 4;
  bf16x8 qfr[6];
  #pragma unroll
  for (int kk = 0; kk < 6; ++kk) {
    int u = kk * 4 + l4;
    qfr[kk] = *(bf16x8*)((char*)plds + l15 * 384 + ((u ^ (l15 & 7)) << 4));
  }
  float ax[4], ay[4], c0[4], av[4], bv[4];
  #pragma unroll
  for (int j = 0; j < 4; ++j) {
    int s = l4 * 4 + j;
    if (s < 8) {
      av[j] = pab[(b * 8 + s) * 2];
      bv[j] = pab[(b * 8 + s) * 2 + 1];
      if (have_bias) {
        float inv = 1.f / (scal_prev[(b * 8 + s) * 4] + 1e-8f);
        float cx = scal_prev[(b * 8 + s) * 4 + 1] * inv;
        float cy2 = scal_prev[(b * 8 + s) * 4 + 2] * inv;
        ax[j] = 16.f * cx; ay[j] = 16.f * cy2; c0[j] = -8.f * (cx * cx + cy2 * cy2);
      } else { ax[j] = 0.f; ay[j] = 0.f; c0[j] = 0.f; }
    } else { av[j] = 0.f; bv[j] = 0.f; ax[j] = 0.f; ay[j] = 0.f; c0[j] = 0.f; }
  }
  float pa[4], px[4], py[4], pg[4];
  #pragma unroll
  for (int j = 0; j < 4; ++j) { pa[j] = 0.f; px[j] = 0.f; py[j] = 0.f; pg[j] = 0.f; }
  for (int tile = w; tile < 16; tile += 4) {
    int t0 = chunk + tile * 16;
    long Tg = (long)b * 256 + (t0 >> 4);
    const u16* kp = fb + (Tg * 24 + l4) * 128 + l15 * 8;
    f32x4 acc = (f32x4){0.f, 0.f, 0.f, 0.f};
    #pragma unroll
    for (int kk = 0; kk < 6; ++kk) {
      bf16x8 bfr = *(const bf16x8*)(kp + kk * 512);
      acc = __builtin_amdgcn_mfma_f32_16x16x32_bf16(qfr[kk], bfr, acc, 0, 0, 0);
    }
    int t = t0 + l15;
    float2 st = stats[((long)b << 12) + t];
    float rstd = st.x, muv = st.y;
    float x = -1.f + (float)(t & 63) * (2.f / 63.f);
    float y = -1.f + (float)(t >> 6) * (2.f / 63.f);
    float m8r2 = -8.f * (x * x + y * y);
    float d4[4];
    #pragma unroll
    for (int j = 0; j < 4; ++j)
      d4[j] = rstd * acc[j] - rstd * muv * av[j] + bv[j] +
              (have_bias ? (ax[j] * x + ay[j] * y + c0[j] + m8r2) : 0.f);
    float o4[4];
    #pragma unroll
    for (int j = 0; j < 4; ++j) o4[j] = __shfl_xor(d4[j], 16);
    float mx = fmaxf(fmaxf(fmaxf(d4[0], d4[1]), fmaxf(d4[2], d4[3])),
                     fmaxf(fmaxf(o4[0], o4[1]), fmaxf(o4[2], o4[3])));
    float e4[4];
    float sum = 0.f;
    #pragma unroll
    for (int j = 0; j < 4; ++j) { e4[j] = __expf(d4[j] - mx); sum += e4[j]; }
    #pragma unroll
    for (int j = 0; j < 4; ++j) sum += __expf(o4[j] - mx);
    float inv = 1.f / sum;
    if (l4 < 2) {
      int tl = tile * 16 + l15;
      #pragma unroll
      for (int j = 0; j < 4; ++j) {
        float a = e4[j] * inv;
        u16 wr = f2bf(a * rstd);
        int s = l4 * 4 + j;
        *(u16*)((char*)attn_lds + ((s * 512 + tl * 2) ^ ((s & 7) << 4))) = wr;
        pa[j] += a; px[j] += a * x; py[j] += a * y;
        pg[j] += bf2f(wr) * muv;
      }
    }
  }
  #pragma unroll
  for (int m = 1; m < 16; m <<= 1) {
    #pragma unroll
    for (int j = 0; j < 4; ++j) {
      pa[j] += __shfl_xor(pa[j], m);
      px[j] += __shfl_xor(px[j], m);
      py[j] += __shfl_xor(py[j], m);
      pg[j] += __shfl_xor(pg[j], m);
    }
  }
  if (l15 == 0 && l4 < 2) {
    #pragma unroll
    for (int j = 0; j < 4; ++j) {
      int s = l4 * 4 + j;
      atomicAdd(&scal_cur[(b * 8 + s) * 4], pa[j]);
      atomicAdd(&scal_cur[(b * 8 + s) * 4 + 1], px[j]);
      atomicAdd(&scal_cur[(b * 8 + s) * 4 + 2], py[j]);
      atomicAdd(&scal_cur[(b * 8 + s) * 4 + 3], pg[j]);
    }
  }
  __syncthreads();
  // ---- PV: U_part[slot][dim] = sum_t w'[slot][t] * f[t][dim] (stores) ----
  int g32base = chunk >> 5;
  float* up = U_part + (size_t)(b * 16 + cy) * 1536;
  #pragma unroll
  for (int ni = 0; ni < 3; ++ni) {
    int nt = w * 3 + ni;
    f32x4 acc = (f32x4){0.f, 0.f, 0.f, 0.f};
    const u16* vp = fd + ((((long)b * 128 + g32base) * 12 + nt) * 64 + l4 * 16 + l15) * 8;
    #pragma unroll
    for (int gl = 0; gl < 8; ++gl) {
      int tl0 = gl * 32 + l4 * 8;
      bf16x8 afr = *(bf16x8*)((char*)attn_lds + ((l15 * 512 + tl0 * 2) ^ ((l15 & 7) << 4)));
      bf16x8 bfr = *(const bf16x8*)(vp + gl * 12 * 64 * 8);
      acc = __builtin_amdgcn_mfma_f32_16x16x32_bf16(afr, bfr, acc, 0, 0, 0);
    }
    if (l4 < 2) {
      #pragma unroll
      for (int j = 0; j < 4; ++j)
        up[(l4 * 4 + j) * 192 + nt * 16 + l15] = acc[j];
    }
  }
}

// ---------------------------------------------------------------------------
// GRU + LN + MLP (+fused next-iter qproj tail).  768 threads.
// First phase sums U_part partials, then upd = ((U-gam)@Wvm + asum*s0v)/asum.
// Tail (do_tail): zero scal_next for own slots, q = LN(out)@Wq*scale,
// p = lfg⊙(Wk@q) -> pbuf, alpha/beta -> pab.
// ---------------------------------------------------------------------------
template <int M>
__device__ void gru_body(int b0, int g, int srow,
                         float* u_l, float* h_l, float* gi_l, float* gh_l,
                         float* hn_l, float* ln_l, float* x1_l, float* out_l, float* st,
                         const float* __restrict__ U_part, const float* __restrict__ scal,
                         const float* __restrict__ Wvm, const float* __restrict__ s0v,
                         const float* __restrict__ sin_,
                         const u16* __restrict__ pWih, const u16* __restrict__ pWhh,
                         const float* __restrict__ bih, const float* __restrict__ bhh,
                         const float* __restrict__ mlng, const float* __restrict__ mlnb,
                         const u16* __restrict__ pW1, const float* __restrict__ b1,
                         const u16* __restrict__ pW2, const float* __restrict__ b2,
                         float* __restrict__ sout,
                         const float* __restrict__ Wq, const float* __restrict__ lsg,
                         const float* __restrict__ lsb, const float* __restrict__ Wk,
                         const float* __restrict__ lfg, const float* __restrict__ s0k,
                         u16* __restrict__ pbuf, float* __restrict__ pab,
                         float* __restrict__ scal_next, int do_tail) {
  int tid = threadIdx.x;
  for (int idx = tid; idx < M * 192; idx += 768) {
    int row = idx / 192, d = idx % 192;
    int gr = b0 * 8 + srow + row;
    float acc = 0.f;
    const float* upb = U_part + (size_t)b0 * 16 * 1536 + (srow + row) * 192 + d;
    #pragma unroll 4
    for (int c = 0; c < 16; ++c) acc += upb[c * 1536];
    hn_l[row * 192 + d] = acc;
    h_l[row * 192 + d] = sin_[gr * DD + d];
  }
  __syncthreads();
  if (tid < M * 192) {
    int row = tid / 192, d = tid % 192;
    int gr = b0 * 8 + srow + row;
    float asum = scal[gr * 4], gam = scal[gr * 4 + 3];
    float inv = 1.f / (asum + 1e-8f);
    float acc = asum * s0v[d];
    const float* ur = hn_l + row * 192;
    #pragma unroll 4
    for (int e = 0; e < DD; ++e) acc += (ur[e] - gam) * Wvm[e * DD + d];
    u_l[row * 192 + d] = acc * inv;
  }
  __syncthreads();
  if (tid < 576) {
    int c = tid;
    const u16* wih = pWih + (size_t)g * 96 * 1152 + c * 2;
    const u16* whh = pWhh + (size_t)g * 96 * 1152 + c * 2;
    float ai[M], ah[M];
    #pragma unroll
    for (int r = 0; r < M; ++r) { ai[r] = 0.f; ah[r] = 0.f; }
    #pragma unroll 4
    for (int e2 = 0; e2 < 96; ++e2) {
      u32 wi = *(const u32*)(wih + e2 * 1152);
      u32 wh = *(const u32*)(whh + e2 * 1152);
      float wi0 = bf2f(wi & 0xffffu), wi1 = bf2f(wi >> 16);
      float wh0 = bf2f(wh & 0xffffu), wh1 = bf2f(wh >> 16);
      #pragma unroll
      for (int r = 0; r < M; ++r) {
        ai[r] += wi0 * u_l[r * 192 + e2 * 2] + wi1 * u_l[r * 192 + e2 * 2 + 1];
        ah[r] += wh0 * h_l[r * 192 + e2 * 2] + wh1 * h_l[r * 192 + e2 * 2 + 1];
      }
    }
    #pragma unroll
    for (int r = 0; r < M; ++r) { gi_l[r * 576 + c] = ai[r]; gh_l[r * 576 + c] = ah[r]; }
  }
  __syncthreads();
  if (tid < M * 192) {
    int row = tid / 192, uu = tid % 192;
    const float* bihg = bih + g * 576;
    const float* bhhg = bhh + g * 576;
    float r_ = sigm(gi_l[row * 576 + uu] + bihg[uu] + gh_l[row * 576 + uu] + bhhg[uu]);
    float z_ = sigm(gi_l[row * 576 + 192 + uu] + bihg[192 + uu] +
                    gh_l[row * 576 + 192 + uu] + bhhg[192 + uu]);
    float nn = gi_l[row * 576 + 384 + uu] + bihg[384 + uu] +
               r_ * (gh_l[row * 576 + 384 + uu] + bhhg[384 + uu]);
    float t = 1.f - 2.f / (__expf(2.f * nn) + 1.f);
    hn_l[row * 192 + uu] = (1.f - z_) * t + z_ * h_l[row * 192 + uu];
  }
  __syncthreads();
  {
    int wv = tid >> 6, lane = tid & 63;
    if (wv < M) {
      float v0 = hn_l[wv * 192 + lane], v1 = hn_l[wv * 192 + lane + 64],
            v2 = hn_l[wv * 192 + lane + 128];
      float s = v0 + v1 + v2, sq = v0 * v0 + v1 * v1 + v2 * v2;
      #pragma unroll
      for (int m = 1; m < 64; m <<= 1) { s += __shfl_xor(s, m); sq += __shfl_xor(sq, m); }
      if (lane == 0) {
        float mu = s * (1.f / 192.f);
        st[wv * 2] = mu;
        st[wv * 2 + 1] = rsqrtf(sq * (1.f / 192.f) - mu * mu + 1e-5f);
      }
    }
  }
  __syncthreads();
  if (tid < M * 192) {
    int row = tid / 192, uu = tid % 192;
    ln_l[row * 192 + uu] = (hn_l[row * 192 + uu] - st[row * 2]) * st[row * 2 + 1] *
                               mlng[g * DD + uu] + mlnb[g * DD + uu];
  }
  __syncthreads();
  {
    int c = tid;
    const u16* w1 = pW1 + (size_t)g * 96 * 1536 + c * 2;
    float a[M];
    #pragma unroll
    for (int r = 0; r < M; ++r) a[r] = 0.f;
    #pragma unroll 4
    for (int e2 = 0; e2 < 96; ++e2) {
      u32 wp = *(const u32*)(w1 + e2 * 1536);
      float w0 = bf2f(wp & 0xffffu), w1f = bf2f(wp >> 16);
      #pragma unroll
      for (int r = 0; r < M; ++r)
        a[r] += w0 * ln_l[r * 192 + e2 * 2] + w1f * ln_l[r * 192 + e2 * 2 + 1];
    }
    float bc = b1[g * HH + c];
    #pragma unroll
    for (int r = 0; r < M; ++r) x1_l[r * 768 + c] = fmaxf(a[r] + bc, 0.f);
  }
  if (tid < M * 192) {
    int row = tid / 192, uu = tid % 192;
    out_l[row * 192 + uu] = hn_l[row * 192 + uu] + b2[g * DD + uu];
  }
  __syncthreads();
  {
    int c = tid % 192, ks = tid / 192;
    const u16* w2 = pW2 + (size_t)g * 384 * 384 + c * 2;
    float a[M];
    #pragma unroll
    for (int r = 0; r < M; ++r) a[r] = 0.f;
    #pragma unroll 4
    for (int e2 = ks * 96; e2 < ks * 96 + 96; ++e2) {
      u32 wp = *(const u32*)(w2 + e2 * 384);
      float w0 = bf2f(wp & 0xffffu), w1f = bf2f(wp >> 16);
      #pragma unroll
      for (int r = 0; r < M; ++r)
        a[r] += w0 * x1_l[r * 768 + e2 * 2] + w1f * x1_l[r * 768 + e2 * 2 + 1];
    }
    #pragma unroll
    for (int r = 0; r < M; ++r) atomicAdd(&out_l[r * 192 + c], a[r]);
  }
  __syncthreads();
  if (tid < M * 192) {
    int row = tid / 192, d = tid % 192;
    sout[(b0 * 8 + srow + row) * DD + d] = out_l[row * 192 + d];
  }
  if (!do_tail) return;
  // ================= fused qproj for next iteration =================
  // zero scal_next for own slots + pab partial accumulators (st[8..13])
  if (tid < M * 4) scal_next[(b0 * 8 + srow + tid / 4) * 4 + (tid & 3)] = 0.f;
  if (tid >= 64 && tid < 64 + 2 * M) st[8 + (tid - 64)] = 0.f;
  // LN stats over out_l rows
  {
    int wv = tid >> 6, lane = tid & 63;
    if (wv < M) {
      float v0 = out_l[wv * 192 + lane], v1 = out_l[wv * 192 + lane + 64],
            v2 = out_l[wv * 192 + lane + 128];
      float s = v0 + v1 + v2, sq = v0 * v0 + v1 * v1 + v2 * v2;
      #pragma unroll
      for (int m = 1; m < 64; m <<= 1) { s += __shfl_xor(s, m); sq += __shfl_xor(sq, m); }
      if (lane == 0) {
        float mu = s * (1.f / 192.f);
        st[wv * 2] = mu;
        st[wv * 2 + 1] = rsqrtf(sq * (1.f / 192.f) - mu * mu + 1e-5f);
      }
    }
  }
  __syncthreads();
  if (tid < M * 192) {
    int row = tid / 192, d = tid % 192;
    ln_l[row * 192 + d] = (out_l[row * 192 + d] - st[row * 2]) * st[row * 2 + 1] *
                              lsg[d] + lsb[d];
  }
  __syncthreads();
  if (tid < M * 192) {
    int row = tid / 192, d = tid % 192;
    float q = 0.f;
    #pragma unroll 4
    for (int e = 0; e < DD; ++e) q += ln_l[row * 192 + e] * Wq[e * DD + d];
    gi_l[row * 192 + d] = q * 0.07216878364870323f;
  }
  __syncthreads();
  if (tid < M * 192) {
    int row = tid / 192, d = tid % 192;
    const float* wr = Wk + (size_t)d * DD;
    const float* qr = gi_l + row * 192;
    float pd = 0.f;
    #pragma unroll 4
    for (int e = 0; e < DD; ++e) pd += wr[e] * qr[e];
    pd *= lfg[d];
    u16 h = f2bf(pd);
    pbuf[(b0 * 16 + srow + row) * DD + d] = h;
    float al = bf2f(h);
    float be = s0k[d] * qr[d];
    #pragma unroll
    for (int m = 1; m < 64; m <<= 1) { al += __shfl_xor(al, m); be += __shfl_xor(be, m); }
    if ((tid & 63) == 0) {
      atomicAdd(&st[8 + row * 2], al);
      atomicAdd(&st[9 + row * 2], be);
    }
  }
  __syncthreads();
  if (tid < M) {
    int bk = b0 * 8 + srow + tid;
    pab[bk * 2] = st[8 + tid * 2];
    pab[bk * 2 + 1] = st[9 + tid * 2];
  }
}

__global__ __launch_bounds__(768) void gru_kernel(
    const float* __restrict__ U_part, const float* __restrict__ scal,
    const float* __restrict__ Wvm, const float* __restrict__ s0v,
    const float* __restrict__ sin_,
    const u16* __restrict__ pWih, const u16* __restrict__ pWhh,
    const float* __restrict__ bih, const float* __restrict__ bhh,
    const float* __restrict__ mlng, const float* __restrict__ mlnb,
    const u16* __restrict__ pW1, const float* __restrict__ b1,
    const u16* __restrict__ pW2, const float* __restrict__ b2,
    float* __restrict__ sout,
    const float* __restrict__ Wq, const float* __restrict__ lsg,
    const float* __restrict__ lsb, const float* __restrict__ Wk,
    const float* __restrict__ lfg, const float* __restrict__ s0k,
    u16* __restrict__ pbuf, float* __restrict__ pab,
    float* __restrict__ scal_next, int do_tail) {
  __shared__ float u_l[3 * 192], h_l[3 * 192], gi_l[3 * 576], gh_l[3 * 576];
  __shared__ float hn_l[3 * 192], ln_l[3 * 192], x1_l[3 * 768], out_l[3 * 192], st[16];
  int b = blockIdx.x, y = blockIdx.y;
  if (y == 0)
    gru_body<1>(b, 0, 0, u_l, h_l, gi_l, gh_l, hn_l, ln_l, x1_l, out_l, st,
                U_part, scal, Wvm, s0v, sin_, pWih, pWhh, bih, bhh, mlng, mlnb,
                pW1, b1, pW2, b2, sout, Wq, lsg, lsb, Wk, lfg, s0k,
                pbuf, pab, scal_next, do_tail);
  else if (y == 1)
    gru_body<1>(b, 2, 7, u_l, h_l, gi_l, gh_l, hn_l, ln_l, x1_l, out_l, st,
                U_part, scal, Wvm, s0v, sin_, pWih, pWhh, bih, bhh, mlng, mlnb,
                pW1, b1, pW2, b2, sout, Wq, lsg, lsb, Wk, lfg, s0k,
                pbuf, pab, scal_next, do_tail);
  else if (y == 2)
    gru_body<3>(b, 1, 1, u_l, h_l, gi_l, gh_l, hn_l, ln_l, x1_l, out_l, st,
                U_part, scal, Wvm, s0v, sin_, pWih, pWhh, bih, bhh, mlng, mlnb,
                pW1, b1, pW2, b2, sout, Wq, lsg, lsb, Wk, lfg, s0k,
                pbuf, pab, scal_next, do_tail);
  else
    gru_body<3>(b, 1, 4, u_l, h_l, gi_l, gh_l, hn_l, ln_l, x1_l, out_l, st,
                U_part, scal, Wvm, s0v, sin_, pWih, pWhh, bih, bhh, mlng, mlnb,
                pW1, b1, pW2, b2, sout, Wq, lsg, lsb, Wk, lfg, s0k,
                pbuf, pab, scal_next, do_tail);
}

// ---------------------------------------------------------------------------
extern "C" void kernel_launch(void* const* d_in, const int* in_sizes, int n_in,
                              void* d_out, int out_size, void* d_ws, size_t ws_size,
                              hipStream_t stream) {
  const float* feat = (const float*)d_in[0];
  const float* slots = (const float*)d_in[1];
  const float* Wk = (const float*)d_in[2];
  const float* Wv = (const float*)d_in[3];
  const float* Wq = (const float*)d_in[4];
  const float* lfg = (const float*)d_in[5];
  const float* lfb = (const float*)d_in[6];
  const float* lsg = (const float*)d_in[7];
  const float* lsb = (const float*)d_in[8];
  const float* gWih = (const float*)d_in[9];
  const float* gWhh = (const float*)d_in[10];
  const float* gbih = (const float*)d_in[11];
  const float* gbhh = (const float*)d_in[12];
  const float* mlng = (const float*)d_in[13];
  const float* mlnb = (const float*)d_in[14];
  const float* W1 = (const float*)d_in[15];
  const float* b1 = (const float*)d_in[16];
  const float* W2 = (const float*)d_in[17];
  const float* b2 = (const float*)d_in[18];
  float* out = (float*)d_out;

  char* ws = (char*)d_ws;
  size_t off = 0;
  auto alloc = [&](size_t bytes) {
    void* p = ws + off;
    off += (bytes + 255) & ~(size_t)255;
    return p;
  };
  u16* fb       = (u16*)alloc((size_t)BB * FF * DD * 2);
  u16* fd       = (u16*)alloc((size_t)BB * DD * FF * 2);
  float2* stats = (float2*)alloc((size_t)BB * FF * 8);
  u16* pbuf     = (u16*)alloc((size_t)BB * 16 * DD * 2);
  float* pab    = (float*)alloc((size_t)BB * 8 * 2 * 4);
  float* U_part = (float*)alloc((size_t)BB * 16 * 8 * DD * 4);
  float* slA    = (float*)alloc((size_t)BB * 8 * DD * 4);
  float* slB    = (float*)alloc((size_t)BB * 8 * DD * 4);
  float* scal0  = (float*)alloc(BB * 8 * 4 * 4);
  float* scal1  = (float*)alloc(BB * 8 * 4 * 4);
  float* Wvm    = (float*)alloc((size_t)DD * DD * 4);
  float* s0v    = (float*)alloc(DD * 4);
  float* s0k    = (float*)alloc(DD * 4);
  u16* pWih     = (u16*)alloc((size_t)3 * 576 * DD * 2);
  u16* pWhh     = (u16*)alloc((size_t)3 * 576 * DD * 2);
  u16* pW1      = (u16*)alloc((size_t)3 * DD * HH * 2);
  u16* pW2      = (u16*)alloc((size_t)3 * HH * DD * 2);

  prep_vw<<<1, 192, 0, stream>>>(Wk, Wv, lfg, lfb, Wvm, s0v, s0k);
  prep_packw<<<dim3(432, 4), 256, 0, stream>>>(gWih, gWhh, W1, W2, pWih, pWhh, pW1, pW2);
  fconv<<<BB * FF / 64, 256, 0, stream>>>(feat, fb, fd, stats);

  float* souts[3] = {slA, slB, out};
  float* scals[2] = {scal0, scal1};

  // iteration 0's q/p from input slots (also zeroes scals[0], pbuf pad rows)
  qproj_kernel<<<BB * 8, 64, 0, stream>>>(slots, Wq, lsg, lsb, Wk, lfg, s0k,
                                          pbuf, pab, scals[0]);
  const float* sin_ = slots;
  for (int it = 0; it < 3; ++it) {
    int cur = it & 1, prev = cur ^ 1;
    attnpv_kernel<<<dim3(BB, 16), 256, 0, stream>>>(fb, fd, pbuf, pab, stats,
                                                    scals[prev], U_part, scals[cur],
                                                    it > 0 ? 1 : 0);
    gru_kernel<<<dim3(BB, 4), 768, 0, stream>>>(U_part, scals[cur], Wvm, s0v, sin_,
                                                pWih, pWhh, gbih, gbhh, mlng, mlnb,
                                                pW1, b1, pW2, b2, souts[it],
                                                Wq, lsg, lsb, Wk, lfg, s0k,
                                                pbuf, pab, scals[prev],
                                                it < 2 ? 1 : 0);
    sin_ = souts[it];
  }
}

// Round 12
// 493.422 us; speedup vs baseline: 1.5701x; 1.0405x over previous
//
#include <hip/hip_runtime.h>

typedef unsigned short u16;
typedef unsigned int u32;

#define BB 64
#define FF 4096
#define DD 192
#define HH 768

typedef __attribute__((ext_vector_type(8))) __bf16 bf16x8;
typedef __attribute__((ext_vector_type(4))) float f32x4;

__device__ __forceinline__ float bf2f(u32 u) {
  union { u32 i; float f; } x; x.i = u << 16; return x.f;
}
__device__ __forceinline__ u16 f2bf(float f) {
  __bf16 h = (__bf16)f;
  return __builtin_bit_cast(u16, h);
}
__device__ __forceinline__ u32 pk2bf(float a, float b) {
  return (u32)f2bf(a) | ((u32)f2bf(b) << 16);
}
__device__ __forceinline__ float sigm(float x) { return 1.f / (1.f + __expf(-x)); }

// ---------------------------------------------------------------------------
// Prep: Wvm[e][d] = g[e]*Wv[e][d] (f32), s0v[d] = b@Wv, s0k[d] = b@Wk.
// ---------------------------------------------------------------------------
__global__ void prep_vw(const float* __restrict__ Wk, const float* __restrict__ Wv,
                        const float* __restrict__ g, const float* __restrict__ bb,
                        float* __restrict__ Wvm, float* __restrict__ s0v,
                        float* __restrict__ s0k) {
  int d = threadIdx.x;  // 0..191
  float av = 0.f, ak = 0.f;
  for (int e = 0; e < DD; ++e) {
    float wv = Wv[e * DD + d];
    Wvm[e * DD + d] = g[e] * wv;
    av += bb[e] * wv;
    ak += bb[e] * Wk[e * DD + d];
  }
  s0v[d] = av; s0k[d] = ak;
}

// Pack GRU/MLP weights to bf16 e-pairs: dst[((g*E2+e/2)*N + n)*2 + (e&1)].
__global__ void prep_packw(const float* __restrict__ Wih, const float* __restrict__ Whh,
                           const float* __restrict__ W1, const float* __restrict__ W2,
                           u16* __restrict__ pWih, u16* __restrict__ pWhh,
                           u16* __restrict__ pW1, u16* __restrict__ pW2) {
  int which = blockIdx.y;
  int total, N, E;
  const float* src; u16* dst; int srcEmajor;
  if (which < 2) { total = 3 * 576 * 192; N = 576; E = 192; srcEmajor = 0;
                   src = which ? Whh : Wih; dst = which ? pWhh : pWih; }
  else if (which == 2) { total = 3 * 192 * 768; N = 768; E = 192; srcEmajor = 1;
                         src = W1; dst = pW1; }
  else { total = 3 * 768 * 192; N = 192; E = 768; srcEmajor = 1; src = W2; dst = pW2; }
  for (int idx = blockIdx.x * 256 + threadIdx.x; idx < total; idx += gridDim.x * 256) {
    int g = idx / (N * E), rem = idx % (N * E);
    int n, e;
    if (srcEmajor) { e = rem / N; n = rem % N; }    // src[g][e][n]
    else { n = rem / E; e = rem % E; }              // src[g][n][e]
    dst[((g * (E / 2) + (e >> 1)) * N + n) * 2 + (e & 1)] = f2bf(src[idx]);
  }
}

// ---------------------------------------------------------------------------
// fconv v3: request-efficient streaming.
// Phase 1: lane-linear 32-B f32 pieces -> bf16 -> XOR-swizzled LDS tile.
// Phase 1b: LN stats recomputed from bf16 tile (4 thr/token + shuffles).
// Phase 2: fb written granule-linear from LDS (1 KB per wave-instruction).
// Phase 3: fd granules gathered from swizzled LDS (as before).
// fb: [Tg][u(24)][tau16][8dims].  fd: [((b*128+g32)*12+nt)*64+l4f*16+(d&15)][8t].
// ---------------------------------------------------------------------------
__global__ __launch_bounds__(256) void fconv(const float* __restrict__ feat,
                                             u16* __restrict__ fb, u16* __restrict__ fd,
                                             float2* __restrict__ stats) {
  __shared__ __align__(16) u16 flds[64 * 192];  // swizzled: tok*384B + ((u8^(tok&7))<<4)
  int tid = threadIdx.x;
  int blk = blockIdx.x;
  // ---- phase 1: coalesced load + swizzled LDS store ----
  const float4* src = (const float4*)(feat + (size_t)blk * 64 * DD);
  #pragma unroll
  for (int i = 0; i < 6; ++i) {
    int q = i * 256 + tid;              // 32-B piece id, 0..1535 (lane-linear)
    float4 a = src[q * 2], b = src[q * 2 + 1];
    uint4 v;
    v.x = pk2bf(a.x, a.y); v.y = pk2bf(a.z, a.w);
    v.z = pk2bf(b.x, b.y); v.w = pk2bf(b.z, b.w);
    int tok = q / 24, u8 = q % 24;
    *(uint4*)((char*)flds + tok * 384 + ((u8 ^ (tok & 7)) << 4)) = v;
  }
  __syncthreads();
  // ---- phase 1b: stats from bf16 tile ----
  {
    int r = tid >> 2, p = tid & 3;
    float s = 0.f, s2 = 0.f;
    #pragma unroll
    for (int i = 0; i < 6; ++i) {
      int u8 = p * 6 + i;
      uint4 v = *(uint4*)((char*)flds + r * 384 + ((u8 ^ (r & 7)) << 4));
      u32 ws[4] = {v.x, v.y, v.z, v.w};
      #pragma unroll
      for (int j = 0; j < 4; ++j) {
        float f0 = bf2f(ws[j] & 0xffffu), f1 = bf2f(ws[j] >> 16);
        s += f0 + f1; s2 += f0 * f0 + f1 * f1;
      }
    }
    s += __shfl_xor(s, 1); s2 += __shfl_xor(s2, 1);
    s += __shfl_xor(s, 2); s2 += __shfl_xor(s2, 2);
    if (p == 0) {
      float mu = s * (1.f / 192.f);
      float rstd = rsqrtf(s2 * (1.f / 192.f) - mu * mu + 1e-5f);
      stats[(size_t)blk * 64 + r] = make_float2(rstd, mu);
    }
  }
  // ---- phase 2: fb, granule-linear (fully coalesced) ----
  #pragma unroll
  for (int i = 0; i < 6; ++i) {
    int s = i * 256 + tid;              // local fb slot, 0..1535
    int tau = s & 15, u = (s >> 4) % 24, Tg_l = s / 384;
    int tok = Tg_l * 16 + tau;
    uint4 v = *(uint4*)((char*)flds + tok * 384 + ((u ^ (tok & 7)) << 4));
    *(uint4*)(fb + ((size_t)blk * 1536 + s) * 8) = v;
  }
  // ---- phase 3: fd granules (8 tokens, 1 dim) from swizzled LDS ----
  int b = blk >> 6;
  #pragma unroll
  for (int i = 0; i < 6; ++i) {
    int idx = tid + i * 256;            // 0..1535
    int tg8 = idx / 192, d = idx % 192;
    u16 h[8];
    #pragma unroll
    for (int j = 0; j < 8; ++j) {
      int tok = tg8 * 8 + j;
      h[j] = *(const u16*)((char*)flds + tok * 384 +
                           (((d >> 3) ^ (tok & 7)) << 4) + (d & 7) * 2);
    }
    uint4 v;
    v.x = (u32)h[0] | ((u32)h[1] << 16);
    v.y = (u32)h[2] | ((u32)h[3] << 16);
    v.z = (u32)h[4] | ((u32)h[5] << 16);
    v.w = (u32)h[6] | ((u32)h[7] << 16);
    int g32 = (blk & 63) * 2 + (tg8 >> 2);
    int l4f = tg8 & 3;
    *(uint4*)(fd + ((((long)b * 128 + g32) * 12 + (d >> 4)) * 64 + l4f * 16 +
                    (d & 15)) * 8) = v;
  }
}

// ---------------------------------------------------------------------------
// Standalone q projection (iteration 0 only): q = LN(slots)@Wq*scale,
// p = lfg ⊙ (Wk@q), alpha = sum bf16(p), beta = s0k·q.
// Also zeroes scal_cur and pbuf rows 8..15.
// ---------------------------------------------------------------------------
__global__ __launch_bounds__(64) void qproj_kernel(
    const float* __restrict__ slots, const float* __restrict__ Wq,
    const float* __restrict__ lsg, const float* __restrict__ lsb,
    const float* __restrict__ Wk, const float* __restrict__ lfg,
    const float* __restrict__ s0k,
    u16* __restrict__ pbuf, float* __restrict__ pab,
    float* __restrict__ scal_cur) {
  __shared__ float ln[192];
  int bk = blockIdx.x;
  int b = bk >> 3, sl = bk & 7;
  int lane = threadIdx.x;
  {
    int gtid = bk * 64 + lane;
    if (gtid < 512) ((float4*)scal_cur)[gtid] = (float4){0.f, 0.f, 0.f, 0.f};
  }
  const float* x = slots + bk * DD;
  float v0 = x[lane], v1 = x[lane + 64], v2 = x[lane + 128];
  float s = v0 + v1 + v2, s2 = v0 * v0 + v1 * v1 + v2 * v2;
  #pragma unroll
  for (int m = 1; m < 64; m <<= 1) { s += __shfl_xor(s, m); s2 += __shfl_xor(s2, m); }
  float mu = s * (1.f / 192.f);
  float rstd = rsqrtf(s2 * (1.f / 192.f) - mu * mu + 1e-5f);
  ln[lane]       = (v0 - mu) * rstd * lsg[lane]       + lsb[lane];
  ln[lane + 64]  = (v1 - mu) * rstd * lsg[lane + 64]  + lsb[lane + 64];
  ln[lane + 128] = (v2 - mu) * rstd * lsg[lane + 128] + lsb[lane + 128];
  __syncthreads();
  float a0 = 0.f, a1 = 0.f, a2 = 0.f;
  for (int e = 0; e < DD; ++e) {
    float le = ln[e];
    a0 += le * Wq[e * DD + lane];
    a1 += le * Wq[e * DD + lane + 64];
    a2 += le * Wq[e * DD + lane + 128];
  }
  __syncthreads();
  const float scale = 0.07216878364870323f;  // 192^-0.5
  ln[lane] = a0 * scale; ln[lane + 64] = a1 * scale; ln[lane + 128] = a2 * scale;
  __syncthreads();
  float al = 0.f, be = 0.f;
  u16 pb[3];
  #pragma unroll
  for (int k3 = 0; k3 < 3; ++k3) {
    int d = lane + k3 * 64;
    const float* wr = Wk + (size_t)d * DD;
    float pd = 0.f;
    for (int e = 0; e < DD; ++e) pd += wr[e] * ln[e];
    pd *= lfg[d];
    u16 h = f2bf(pd);
    pb[k3] = h;
    al += bf2f(h);
    be += s0k[d] * ln[d];
  }
  #pragma unroll
  for (int m = 1; m < 64; m <<= 1) { al += __shfl_xor(al, m); be += __shfl_xor(be, m); }
  #pragma unroll
  for (int k3 = 0; k3 < 3; ++k3)
    pbuf[(b * 16 + sl) * DD + lane + k3 * 64] = pb[k3];
  if (lane < 24) *(uint4*)(pbuf + (b * 16 + 8 + sl) * DD + lane * 8) = (uint4){0, 0, 0, 0};
  if (lane == 0) { pab[bk * 2] = al; pab[bk * 2 + 1] = be; }
}

// ---------------------------------------------------------------------------
// Fused attention + update on raw features:
// dots = rstd*(f.p) - rstd*mu*alpha + beta (+bias) -> softmax over 8 ->
// w' = attn*rstd to LDS -> PV MFMA -> U_part stores (no atomics).
// grid (B, 16): 256 tokens per block.
// ---------------------------------------------------------------------------
__global__ __launch_bounds__(256) void attnpv_kernel(
    const u16* __restrict__ fb, const u16* __restrict__ fd,
    const u16* __restrict__ pbuf, const float* __restrict__ pab,
    const float2* __restrict__ stats,
    const float* __restrict__ scal_prev,
    float* __restrict__ U_part, float* __restrict__ scal_cur, int have_bias) {
  __shared__ __align__(16) u16 plds[16 * 192];
  __shared__ __align__(16) u16 attn_lds[16 * 256];   // [slot][token], XOR-swizzled
  int b = blockIdx.x, cy = blockIdx.y;
  int chunk = cy * 256;
  int tid = threadIdx.x;
  #pragma unroll
  for (int i = 0; i < 2; ++i) {
    int g = tid + i * 256;
    if (g < 384) {
      int s = g / 24, u = g % 24;
      uint4 v = *(const uint4*)(pbuf + ((b * 16 + s) * DD + u * 8));
      *(uint4*)((char*)plds + s * 384 + ((u ^ (s & 7)) << 4)) = v;
    }
  }
  *(uint4*)((char*)attn_lds + 4096 + tid * 16) = (uint4){0, 0, 0, 0};
  __syncthreads();
  int w = tid >> 6, lane = tid & 63;
  int l15 = lane & 15, l4 = lane >> 4;
  bf16x8 qfr[6];
  #pragma unroll
  for (int kk = 0; kk < 6; ++kk) {
    int u = kk * 4 + l4;
    qfr[kk] = *(bf16x8*)((char*)plds + l15 * 384 + ((u ^ (l15 & 7)) << 4));
  }
  float ax[4], ay[4], c0[4], av[4], bv[4];
  #pragma unroll
  for (int j = 0; j < 4; ++j) {
    int s = l4 * 4 + j;
    if (s < 8) {
      av[j] = pab[(b * 8 + s) * 2];
      bv[j] = pab[(b * 8 + s) * 2 + 1];
      if (have_bias) {
        float inv = 1.f / (scal_prev[(b * 8 + s) * 4] + 1e-8f);
        float cx = scal_prev[(b * 8 + s) * 4 + 1] * inv;
        float cy2 = scal_prev[(b * 8 + s) * 4 + 2] * inv;
        ax[j] = 16.f * cx; ay[j] = 16.f * cy2; c0[j] = -8.f * (cx * cx + cy2 * cy2);
      } else { ax[j] = 0.f; ay[j] = 0.f; c0[j] = 0.f; }
    } else { av[j] = 0.f; bv[j] = 0.f; ax[j] = 0.f; ay[j] = 0.f; c0[j] = 0.f; }
  }
  float pa[4], px[4], py[4], pg[4];
  #pragma unroll
  for (int j = 0; j < 4; ++j) { pa[j] = 0.f; px[j] = 0.f; py[j] = 0.f; pg[j] = 0.f; }
  for (int tile = w; tile < 16; tile += 4) {
    int t0 = chunk + tile * 16;
    long Tg = (long)b * 256 + (t0 >> 4);
    const u16* kp = fb + (Tg * 24 + l4) * 128 + l15 * 8;
    f32x4 acc = (f32x4){0.f, 0.f, 0.f, 0.f};
    #pragma unroll
    for (int kk = 0; kk < 6; ++kk) {
      bf16x8 bfr = *(const bf16x8*)(kp + kk * 512);
      acc = __builtin_amdgcn_mfma_f32_16x16x32_bf16(qfr[kk], bfr, acc, 0, 0, 0);
    }
    int t = t0 + l15;
    float2 st = stats[((long)b << 12) + t];
    float rstd = st.x, muv = st.y;
    float x = -1.f + (float)(t & 63) * (2.f / 63.f);
    float y = -1.f + (float)(t >> 6) * (2.f / 63.f);
    float m8r2 = -8.f * (x * x + y * y);
    float d4[4];
    #pragma unroll
    for (int j = 0; j < 4; ++j)
      d4[j] = rstd * acc[j] - rstd * muv * av[j] + bv[j] +
              (have_bias ? (ax[j] * x + ay[j] * y + c0[j] + m8r2) : 0.f);
    float o4[4];
    #pragma unroll
    for (int j = 0; j < 4; ++j) o4[j] = __shfl_xor(d4[j], 16);
    float mx = fmaxf(fmaxf(fmaxf(d4[0], d4[1]), fmaxf(d4[2], d4[3])),
                     fmaxf(fmaxf(o4[0], o4[1]), fmaxf(o4[2], o4[3])));
    float e4[4];
    float sum = 0.f;
    #pragma unroll
    for (int j = 0; j < 4; ++j) { e4[j] = __expf(d4[j] - mx); sum += e4[j]; }
    #pragma unroll
    for (int j = 0; j < 4; ++j) sum += __expf(o4[j] - mx);
    float inv = 1.f / sum;
    if (l4 < 2) {
      int tl = tile * 16 + l15;
      #pragma unroll
      for (int j = 0; j < 4; ++j) {
        float a = e4[j] * inv;
        u16 wr = f2bf(a * rstd);
        int s = l4 * 4 + j;
        *(u16*)((char*)attn_lds + ((s * 512 + tl * 2) ^ ((s & 7) << 4))) = wr;
        pa[j] += a; px[j] += a * x; py[j] += a * y;
        pg[j] += bf2f(wr) * muv;
      }
    }
  }
  #pragma unroll
  for (int m = 1; m < 16; m <<= 1) {
    #pragma unroll
    for (int j = 0; j < 4; ++j) {
      pa[j] += __shfl_xor(pa[j], m);
      px[j] += __shfl_xor(px[j], m);
      py[j] += __shfl_xor(py[j], m);
      pg[j] += __shfl_xor(pg[j], m);
    }
  }
  if (l15 == 0 && l4 < 2) {
    #pragma unroll
    for (int j = 0; j < 4; ++j) {
      int s = l4 * 4 + j;
      atomicAdd(&scal_cur[(b * 8 + s) * 4], pa[j]);
      atomicAdd(&scal_cur[(b * 8 + s) * 4 + 1], px[j]);
      atomicAdd(&scal_cur[(b * 8 + s) * 4 + 2], py[j]);
      atomicAdd(&scal_cur[(b * 8 + s) * 4 + 3], pg[j]);
    }
  }
  __syncthreads();
  // ---- PV: U_part[slot][dim] = sum_t w'[slot][t] * f[t][dim] (stores) ----
  int g32base = chunk >> 5;
  float* up = U_part + (size_t)(b * 16 + cy) * 1536;
  #pragma unroll
  for (int ni = 0; ni < 3; ++ni) {
    int nt = w * 3 + ni;
    f32x4 acc = (f32x4){0.f, 0.f, 0.f, 0.f};
    const u16* vp = fd + ((((long)b * 128 + g32base) * 12 + nt) * 64 + l4 * 16 + l15) * 8;
    #pragma unroll
    for (int gl = 0; gl < 8; ++gl) {
      int tl0 = gl * 32 + l4 * 8;
      bf16x8 afr = *(bf16x8*)((char*)attn_lds + ((l15 * 512 + tl0 * 2) ^ ((l15 & 7) << 4)));
      bf16x8 bfr = *(const bf16x8*)(vp + gl * 12 * 64 * 8);
      acc = __builtin_amdgcn_mfma_f32_16x16x32_bf16(afr, bfr, acc, 0, 0, 0);
    }
    if (l4 < 2) {
      #pragma unroll
      for (int j = 0; j < 4; ++j)
        up[(l4 * 4 + j) * 192 + nt * 16 + l15] = acc[j];
    }
  }
}

// ---------------------------------------------------------------------------
// GRU + LN + MLP (+fused next-iter qproj tail).  768 threads.
// First phase sums U_part partials, then upd = ((U-gam)@Wvm + asum*s0v)/asum.
// Tail (do_tail): zero scal_next for own slots, q = LN(out)@Wq*scale,
// p = lfg⊙(Wk@q) -> pbuf, alpha/beta -> pab.
// ---------------------------------------------------------------------------
template <int M>
__device__ void gru_body(int b0, int g, int srow,
                         float* u_l, float* h_l, float* gi_l, float* gh_l,
                         float* hn_l, float* ln_l, float* x1_l, float* out_l, float* st,
                         const float* __restrict__ U_part, const float* __restrict__ scal,
                         const float* __restrict__ Wvm, const float* __restrict__ s0v,
                         const float* __restrict__ sin_,
                         const u16* __restrict__ pWih, const u16* __restrict__ pWhh,
                         const float* __restrict__ bih, const float* __restrict__ bhh,
                         const float* __restrict__ mlng, const float* __restrict__ mlnb,
                         const u16* __restrict__ pW1, const float* __restrict__ b1,
                         const u16* __restrict__ pW2, const float* __restrict__ b2,
                         float* __restrict__ sout,
                         const float* __restrict__ Wq, const float* __restrict__ lsg,
                         const float* __restrict__ lsb, const float* __restrict__ Wk,
                         const float* __restrict__ lfg, const float* __restrict__ s0k,
                         u16* __restrict__ pbuf, float* __restrict__ pab,
                         float* __restrict__ scal_next, int do_tail) {
  int tid = threadIdx.x;
  for (int idx = tid; idx < M * 192; idx += 768) {
    int row = idx / 192, d = idx % 192;
    int gr = b0 * 8 + srow + row;
    float acc = 0.f;
    const float* upb = U_part + (size_t)b0 * 16 * 1536 + (srow + row) * 192 + d;
    #pragma unroll 4
    for (int c = 0; c < 16; ++c) acc += upb[c * 1536];
    hn_l[row * 192 + d] = acc;
    h_l[row * 192 + d] = sin_[gr * DD + d];
  }
  __syncthreads();
  if (tid < M * 192) {
    int row = tid / 192, d = tid % 192;
    int gr = b0 * 8 + srow + row;
    float asum = scal[gr * 4], gam = scal[gr * 4 + 3];
    float inv = 1.f / (asum + 1e-8f);
    float acc = asum * s0v[d];
    const float* ur = hn_l + row * 192;
    #pragma unroll 4
    for (int e = 0; e < DD; ++e) acc += (ur[e] - gam) * Wvm[e * DD + d];
    u_l[row * 192 + d] = acc * inv;
  }
  __syncthreads();
  if (tid < 576) {
    int c = tid;
    const u16* wih = pWih + (size_t)g * 96 * 1152 + c * 2;
    const u16* whh = pWhh + (size_t)g * 96 * 1152 + c * 2;
    float ai[M], ah[M];
    #pragma unroll
    for (int r = 0; r < M; ++r) { ai[r] = 0.f; ah[r] = 0.f; }
    #pragma unroll 4
    for (int e2 = 0; e2 < 96; ++e2) {
      u32 wi = *(const u32*)(wih + e2 * 1152);
      u32 wh = *(const u32*)(whh + e2 * 1152);
      float wi0 = bf2f(wi & 0xffffu), wi1 = bf2f(wi >> 16);
      float wh0 = bf2f(wh & 0xffffu), wh1 = bf2f(wh >> 16);
      #pragma unroll
      for (int r = 0; r < M; ++r) {
        ai[r] += wi0 * u_l[r * 192 + e2 * 2] + wi1 * u_l[r * 192 + e2 * 2 + 1];
        ah[r] += wh0 * h_l[r * 192 + e2 * 2] + wh1 * h_l[r * 192 + e2 * 2 + 1];
      }
    }
    #pragma unroll
    for (int r = 0; r < M; ++r) { gi_l[r * 576 + c] = ai[r]; gh_l[r * 576 + c] = ah[r]; }
  }
  __syncthreads();
  if (tid < M * 192) {
    int row = tid / 192, uu = tid % 192;
    const float* bihg = bih + g * 576;
    const float* bhhg = bhh + g * 576;
    float r_ = sigm(gi_l[row * 576 + uu] + bihg[uu] + gh_l[row * 576 + uu] + bhhg[uu]);
    float z_ = sigm(gi_l[row * 576 + 192 + uu] + bihg[192 + uu] +
                    gh_l[row * 576 + 192 + uu] + bhhg[192 + uu]);
    float nn = gi_l[row * 576 + 384 + uu] + bihg[384 + uu] +
               r_ * (gh_l[row * 576 + 384 + uu] + bhhg[384 + uu]);
    float t = 1.f - 2.f / (__expf(2.f * nn) + 1.f);
    hn_l[row * 192 + uu] = (1.f - z_) * t + z_ * h_l[row * 192 + uu];
  }
  __syncthreads();
  {
    int wv = tid >> 6, lane = tid & 63;
    if (wv < M) {
      float v0 = hn_l[wv * 192 + lane], v1 = hn_l[wv * 192 + lane + 64],
            v2 = hn_l[wv * 192 + lane + 128];
      float s = v0 + v1 + v2, sq = v0 * v0 + v1 * v1 + v2 * v2;
      #pragma unroll
      for (int m = 1; m < 64; m <<= 1) { s += __shfl_xor(s, m); sq += __shfl_xor(sq, m); }
      if (lane == 0) {
        float mu = s * (1.f / 192.f);
        st[wv * 2] = mu;
        st[wv * 2 + 1] = rsqrtf(sq * (1.f / 192.f) - mu * mu + 1e-5f);
      }
    }
  }
  __syncthreads();
  if (tid < M * 192) {
    int row = tid / 192, uu = tid % 192;
    ln_l[row * 192 + uu] = (hn_l[row * 192 + uu] - st[row * 2]) * st[row * 2 + 1] *
                               mlng[g * DD + uu] + mlnb[g * DD + uu];
  }
  __syncthreads();
  {
    int c = tid;
    const u16* w1 = pW1 + (size_t)g * 96 * 1536 + c * 2;
    float a[M];
    #pragma unroll
    for (int r = 0; r < M; ++r) a[r] = 0.f;
    #pragma unroll 4
    for (int e2 = 0; e2 < 96; ++e2) {
      u32 wp = *(const u32*)(w1 + e2 * 1536);
      float w0 = bf2f(wp & 0xffffu), w1f = bf2f(wp >> 16);
      #pragma unroll
      for (int r = 0; r < M; ++r)
        a[r] += w0 * ln_l[r * 192 + e2 * 2] + w1f * ln_l[r * 192 + e2 * 2 + 1];
    }
    float bc = b1[g * HH + c];
    #pragma unroll
    for (int r = 0; r < M; ++r) x1_l[r * 768 + c] = fmaxf(a[r] + bc, 0.f);
  }
  if (tid < M * 192) {
    int row = tid / 192, uu = tid % 192;
    out_l[row * 192 + uu] = hn_l[row * 192 + uu] + b2[g * DD + uu];
  }
  __syncthreads();
  {
    int c = tid % 192, ks = tid / 192;
    const u16* w2 = pW2 + (size_t)g * 384 * 384 + c * 2;
    float a[M];
    #pragma unroll
    for (int r = 0; r < M; ++r) a[r] = 0.f;
    #pragma unroll 4
    for (int e2 = ks * 96; e2 < ks * 96 + 96; ++e2) {
      u32 wp = *(const u32*)(w2 + e2 * 384);
      float w0 = bf2f(wp & 0xffffu), w1f = bf2f(wp >> 16);
      #pragma unroll
      for (int r = 0; r < M; ++r)
        a[r] += w0 * x1_l[r * 768 + e2 * 2] + w1f * x1_l[r * 768 + e2 * 2 + 1];
    }
    #pragma unroll
    for (int r = 0; r < M; ++r) atomicAdd(&out_l[r * 192 + c], a[r]);
  }
  __syncthreads();
  if (tid < M * 192) {
    int row = tid / 192, d = tid % 192;
    sout[(b0 * 8 + srow + row) * DD + d] = out_l[row * 192 + d];
  }
  if (!do_tail) return;
  // ================= fused qproj for next iteration =================
  if (tid < M * 4) scal_next[(b0 * 8 + srow + tid / 4) * 4 + (tid & 3)] = 0.f;
  if (tid >= 64 && tid < 64 + 2 * M) st[8 + (tid - 64)] = 0.f;
  {
    int wv = tid >> 6, lane = tid & 63;
    if (wv < M) {
      float v0 = out_l[wv * 192 + lane], v1 = out_l[wv * 192 + lane + 64],
            v2 = out_l[wv * 192 + lane + 128];
      float s = v0 + v1 + v2, sq = v0 * v0 + v1 * v1 + v2 * v2;
      #pragma unroll
      for (int m = 1; m < 64; m <<= 1) { s += __shfl_xor(s, m); sq += __shfl_xor(sq, m); }
      if (lane == 0) {
        float mu = s * (1.f / 192.f);
        st[wv * 2] = mu;
        st[wv * 2 + 1] = rsqrtf(sq * (1.f / 192.f) - mu * mu + 1e-5f);
      }
    }
  }
  __syncthreads();
  if (tid < M * 192) {
    int row = tid / 192, d = tid % 192;
    ln_l[row * 192 + d] = (out_l[row * 192 + d] - st[row * 2]) * st[row * 2 + 1] *
                              lsg[d] + lsb[d];
  }
  __syncthreads();
  if (tid < M * 192) {
    int row = tid / 192, d = tid % 192;
    float q = 0.f;
    #pragma unroll 4
    for (int e = 0; e < DD; ++e) q += ln_l[row * 192 + e] * Wq[e * DD + d];
    gi_l[row * 192 + d] = q * 0.07216878364870323f;
  }
  __syncthreads();
  if (tid < M * 192) {
    int row = tid / 192, d = tid % 192;
    const float* wr = Wk + (size_t)d * DD;
    const float* qr = gi_l + row * 192;
    float pd = 0.f;
    #pragma unroll 4
    for (int e = 0; e < DD; ++e) pd += wr[e] * qr[e];
    pd *= lfg[d];
    u16 h = f2bf(pd);
    pbuf[(b0 * 16 + srow + row) * DD + d] = h;
    float al = bf2f(h);
    float be = s0k[d] * qr[d];
    #pragma unroll
    for (int m = 1; m < 64; m <<= 1) { al += __shfl_xor(al, m); be += __shfl_xor(be, m); }
    if ((tid & 63) == 0) {
      atomicAdd(&st[8 + row * 2], al);
      atomicAdd(&st[9 + row * 2], be);
    }
  }
  __syncthreads();
  if (tid < M) {
    int bk = b0 * 8 + srow + tid;
    pab[bk * 2] = st[8 + tid * 2];
    pab[bk * 2 + 1] = st[9 + tid * 2];
  }
}

__global__ __launch_bounds__(768) void gru_kernel(
    const float* __restrict__ U_part, const float* __restrict__ scal,
    const float* __restrict__ Wvm, const float* __restrict__ s0v,
    const float* __restrict__ sin_,
    const u16* __restrict__ pWih, const u16* __restrict__ pWhh,
    const float* __restrict__ bih, const float* __restrict__ bhh,
    const float* __restrict__ mlng, const float* __restrict__ mlnb,
    const u16* __restrict__ pW1, const float* __restrict__ b1,
    const u16* __restrict__ pW2, const float* __restrict__ b2,
    float* __restrict__ sout,
    const float* __restrict__ Wq, const float* __restrict__ lsg,
    const float* __restrict__ lsb, const float* __restrict__ Wk,
    const float* __restrict__ lfg, const float* __restrict__ s0k,
    u16* __restrict__ pbuf, float* __restrict__ pab,
    float* __restrict__ scal_next, int do_tail) {
  __shared__ float u_l[3 * 192], h_l[3 * 192], gi_l[3 * 576], gh_l[3 * 576];
  __shared__ float hn_l[3 * 192], ln_l[3 * 192], x1_l[3 * 768], out_l[3 * 192], st[16];
  int b = blockIdx.x, y = blockIdx.y;
  if (y == 0)
    gru_body<1>(b, 0, 0, u_l, h_l, gi_l, gh_l, hn_l, ln_l, x1_l, out_l, st,
                U_part, scal, Wvm, s0v, sin_, pWih, pWhh, bih, bhh, mlng, mlnb,
                pW1, b1, pW2, b2, sout, Wq, lsg, lsb, Wk, lfg, s0k,
                pbuf, pab, scal_next, do_tail);
  else if (y == 1)
    gru_body<1>(b, 2, 7, u_l, h_l, gi_l, gh_l, hn_l, ln_l, x1_l, out_l, st,
                U_part, scal, Wvm, s0v, sin_, pWih, pWhh, bih, bhh, mlng, mlnb,
                pW1, b1, pW2, b2, sout, Wq, lsg, lsb, Wk, lfg, s0k,
                pbuf, pab, scal_next, do_tail);
  else if (y == 2)
    gru_body<3>(b, 1, 1, u_l, h_l, gi_l, gh_l, hn_l, ln_l, x1_l, out_l, st,
                U_part, scal, Wvm, s0v, sin_, pWih, pWhh, bih, bhh, mlng, mlnb,
                pW1, b1, pW2, b2, sout, Wq, lsg, lsb, Wk, lfg, s0k,
                pbuf, pab, scal_next, do_tail);
  else
    gru_body<3>(b, 1, 4, u_l, h_l, gi_l, gh_l, hn_l, ln_l, x1_l, out_l, st,
                U_part, scal, Wvm, s0v, sin_, pWih, pWhh, bih, bhh, mlng, mlnb,
                pW1, b1, pW2, b2, sout, Wq, lsg, lsb, Wk, lfg, s0k,
                pbuf, pab, scal_next, do_tail);
}

// ---------------------------------------------------------------------------
extern "C" void kernel_launch(void* const* d_in, const int* in_sizes, int n_in,
                              void* d_out, int out_size, void* d_ws, size_t ws_size,
                              hipStream_t stream) {
  const float* feat = (const float*)d_in[0];
  const float* slots = (const float*)d_in[1];
  const float* Wk = (const float*)d_in[2];
  const float* Wv = (const float*)d_in[3];
  const float* Wq = (const float*)d_in[4];
  const float* lfg = (const float*)d_in[5];
  const float* lfb = (const float*)d_in[6];
  const float* lsg = (const float*)d_in[7];
  const float* lsb = (const float*)d_in[8];
  const float* gWih = (const float*)d_in[9];
  const float* gWhh = (const float*)d_in[10];
  const float* gbih = (const float*)d_in[11];
  const float* gbhh = (const float*)d_in[12];
  const float* mlng = (const float*)d_in[13];
  const float* mlnb = (const float*)d_in[14];
  const float* W1 = (const float*)d_in[15];
  const float* b1 = (const float*)d_in[16];
  const float* W2 = (const float*)d_in[17];
  const float* b2 = (const float*)d_in[18];
  float* out = (float*)d_out;

  char* ws = (char*)d_ws;
  size_t off = 0;
  auto alloc = [&](size_t bytes) {
    void* p = ws + off;
    off += (bytes + 255) & ~(size_t)255;
    return p;
  };
  u16* fb       = (u16*)alloc((size_t)BB * FF * DD * 2);
  u16* fd       = (u16*)alloc((size_t)BB * DD * FF * 2);
  float2* stats = (float2*)alloc((size_t)BB * FF * 8);
  u16* pbuf     = (u16*)alloc((size_t)BB * 16 * DD * 2);
  float* pab    = (float*)alloc((size_t)BB * 8 * 2 * 4);
  float* U_part = (float*)alloc((size_t)BB * 16 * 8 * DD * 4);
  float* slA    = (float*)alloc((size_t)BB * 8 * DD * 4);
  float* slB    = (float*)alloc((size_t)BB * 8 * DD * 4);
  float* scal0  = (float*)alloc(BB * 8 * 4 * 4);
  float* scal1  = (float*)alloc(BB * 8 * 4 * 4);
  float* Wvm    = (float*)alloc((size_t)DD * DD * 4);
  float* s0v    = (float*)alloc(DD * 4);
  float* s0k    = (float*)alloc(DD * 4);
  u16* pWih     = (u16*)alloc((size_t)3 * 576 * DD * 2);
  u16* pWhh     = (u16*)alloc((size_t)3 * 576 * DD * 2);
  u16* pW1      = (u16*)alloc((size_t)3 * DD * HH * 2);
  u16* pW2      = (u16*)alloc((size_t)3 * HH * DD * 2);

  prep_vw<<<1, 192, 0, stream>>>(Wk, Wv, lfg, lfb, Wvm, s0v, s0k);
  prep_packw<<<dim3(432, 4), 256, 0, stream>>>(gWih, gWhh, W1, W2, pWih, pWhh, pW1, pW2);
  fconv<<<BB * FF / 64, 256, 0, stream>>>(feat, fb, fd, stats);

  float* souts[3] = {slA, slB, out};
  float* scals[2] = {scal0, scal1};

  // iteration 0's q/p from input slots (also zeroes scals[0], pbuf pad rows)
  qproj_kernel<<<BB * 8, 64, 0, stream>>>(slots, Wq, lsg, lsb, Wk, lfg, s0k,
                                          pbuf, pab, scals[0]);
  const float* sin_ = slots;
  for (int it = 0; it < 3; ++it) {
    int cur = it & 1, prev = cur ^ 1;
    attnpv_kernel<<<dim3(BB, 16), 256, 0, stream>>>(fb, fd, pbuf, pab, stats,
                                                    scals[prev], U_part, scals[cur],
                                                    it > 0 ? 1 : 0);
    gru_kernel<<<dim3(BB, 4), 768, 0, stream>>>(U_part, scals[cur], Wvm, s0v, sin_,
                                                pWih, pWhh, gbih, gbhh, mlng, mlnb,
                                                pW1, b1, pW2, b2, souts[it],
                                                Wq, lsg, lsb, Wk, lfg, s0k,
                                                pbuf, pab, scals[prev],
                                                it < 2 ? 1 : 0);
    sin_ = souts[it];
  }
}